// Round 15
// baseline (92.995 us; speedup 1.0000x reference)
//
#include <hip/hip_runtime.h>

#define LEN 4096
#define BATCH 32
#define CH 256
#define REPN 198
#define GHOSTN 58
#define NROW (REPN * BATCH)     /* 6336 */
#define NGHOST (GHOSTN * BATCH) /* 1856 */

typedef float f32x4 __attribute__((ext_vector_type(4)));

// ---------------------------------------------------------------------------
// COMPILE-TIME numpy-legacy RNG replication (verified rounds 1-8):
// np.random.seed(123); np.random.choice(256, 58, replace=False)
// ---------------------------------------------------------------------------
struct MTState { unsigned mt[624]; int mti; };
struct Tab { int rep[REPN]; int ghost[GHOSTN]; };

static constexpr unsigned mt_next(MTState& s) {
    if (s.mti >= 624) {
        for (int k = 0; k < 624; ++k) {
            unsigned y = (s.mt[k] & 0x80000000u) | (s.mt[(k + 1) % 624] & 0x7fffffffu);
            s.mt[k] = s.mt[(k + 397) % 624] ^ (y >> 1) ^ ((y & 1u) ? 0x9908b0dfu : 0u);
        }
        s.mti = 0;
    }
    unsigned y = s.mt[s.mti++];
    y ^= y >> 11;
    y ^= (y << 7) & 0x9d2c5680u;
    y ^= (y << 15) & 0xefc60000u;
    y ^= y >> 18;
    return y;
}

static constexpr Tab make_tab() {
    MTState s{};
    s.mt[0] = 123u;
    for (int i = 1; i < 624; ++i)
        s.mt[i] = 1812433253u * (s.mt[i - 1] ^ (s.mt[i - 1] >> 30)) + (unsigned)i;
    s.mti = 624;
    int perm[256] = {};
    for (int i = 0; i < 256; ++i) perm[i] = i;
    for (int i = 255; i > 0; --i) {
        unsigned mask = (unsigned)i;
        mask |= mask >> 1; mask |= mask >> 2; mask |= mask >> 4;
        mask |= mask >> 8; mask |= mask >> 16;
        unsigned j = 0;
        do { j = mt_next(s) & mask; } while (j > (unsigned)i);
        int t = perm[i]; perm[i] = perm[j]; perm[j] = t;
    }
    bool g[256] = {};
    for (int k = 0; k < GHOSTN; ++k) g[perm[k]] = true;
    Tab t{};
    int rc = 0, gc = 0;
    for (int c = 0; c < 256; ++c) {
        if (g[c]) t.ghost[gc++] = c;
        else      t.rep[rc++] = c;
    }
    return t;
}

__constant__ Tab d_tab = make_tab();

// c1[d] = wb[d/3][d%3] (x1 filter, offsets d-7); c2[d] = wb[4-d/3][d%3]
// (x2 = group-reversed filter, same offsets). Verified mapping:
//   x1[l] = sum_d c1[d] x[l+d-7], group i = d/3 gated on 0 <= l-6+3i < LEN
//   x2[l] = sum_d c2[d] x[l+d-7], tap-d gate is the SAME (l-6+3*(d/3))
//   x3[l] = middle 3-tap (d = 6..8 of c1), ungated.
#define C1F(D) wb[(D) / 3][(D) % 3]
#define C2F(D) wb[4 - (D) / 3][(D) % 3]

// ===========================================================================
// Pass 1 (R15) — autocorrelation stats (R11-R14 algebra, correctness-proven)
// at QUARTER-ROW PER WAVE: block = 1 row = 4 waves x 1024 elems (16/lane).
// R14 (half-row) was +5.5us; granularity is the live lever. Corrections:
// wave 0 lanes 0-12 take left outputs, wave 3 lanes 0-12 take right.
// 4-way LDS combine, one end-of-block barrier after all mem/FMA work.
//   blocks [0, 6336)      : one rep row each
//   blocks [6336, 8192)   : ghost copy, one row per block
// ===========================================================================
__global__ __launch_bounds__(256) void pass1_kernel(const float* __restrict__ x,
                                                    const float* __restrict__ w1,
                                                    const float* __restrict__ w2,
                                                    float* __restrict__ stats_ws,
                                                    float* __restrict__ out) {
    const int blk = blockIdx.x;
    if (blk >= NROW) {
        // ghost pass-through: NT load (never re-read), plain store
        const int g = (blk - NROW) % GHOSTN;
        const int b = (blk - NROW) / GHOSTN;
        const int ch = d_tab.ghost[g];
        const f32x4* src = (const f32x4*)(x + ((size_t)b * CH + ch) * LEN);
        f32x4* dst = (f32x4*)(out + ((size_t)b * CH + REPN + g) * LEN);
#pragma unroll
        for (int k = 0; k < 4; ++k) {
            f32x4 t = __builtin_nontemporal_load(&src[threadIdx.x + 256 * k]);
            dst[threadIdx.x + 256 * k] = t;
        }
        return;
    }

    __shared__ float comb[4][22];
    const int widx = threadIdx.x >> 6;
    const int lane = threadIdx.x & 63;
    const int r = blk % REPN;
    const int b = blk / REPN;
    const float* row = x + ((size_t)b * CH + d_tab.rep[r]) * LEN;

    // ---- main accumulation: A[0..14], Sx over this lane's 16 elements ----
    float A[15];
#pragma unroll
    for (int dl = 0; dl < 15; ++dl) A[dl] = 0.f;
    float SX = 0.f;
    float B0[8], B1[8], B2[8], B3[8];
    const int base = (widx << 10) + (lane << 4);

// 8-float chunk load (2x dwordx4); chunks are 8-aligned so a chunk is either
// fully in-range or fully OOB (halo past row end) -> zeros.
#define LOAD8(DST, OFF)                                                           \
    {                                                                             \
        if ((OFF) < LEN) {                                                        \
            const f32x4* q4_ = (const f32x4*)(row + (OFF));                       \
            f32x4 u0_ = q4_[0], u1_ = q4_[1];                                     \
            DST[0] = u0_.x; DST[1] = u0_.y; DST[2] = u0_.z; DST[3] = u0_.w;       \
            DST[4] = u1_.x; DST[5] = u1_.y; DST[6] = u1_.z; DST[7] = u1_.w;       \
        } else {                                                                  \
            _Pragma("unroll")                                                     \
            for (int t = 0; t < 8; ++t) DST[t] = 0.f;                             \
        }                                                                         \
    }

// A[dl] += x[u]x[u+dl] for u = P's 8 elements; window = P[8] ++ Q[8] ++ R[0..5]
#define ACC8(P, Q, R)                                                             \
    {                                                                             \
        _Pragma("unroll")                                                         \
        for (int j = 0; j < 8; ++j) {                                             \
            const float xj_ = P[j];                                               \
            SX += xj_;                                                            \
            _Pragma("unroll")                                                     \
            for (int dl = 0; dl < 15; ++dl) {                                     \
                const int t_ = j + dl;                                            \
                const float xd_ = (t_ < 8) ? P[t_]                                \
                                 : (t_ < 16) ? Q[t_ - 8] : R[t_ - 16];            \
                A[dl] = fmaf(xj_, xd_, A[dl]);                                    \
            }                                                                     \
        }                                                                         \
    }

    // all 4 chunks issued up front, then 2 ACC8
    LOAD8(B0, base);
    LOAD8(B1, base + 8);
    LOAD8(B2, base + 16);
    LOAD8(B3, base + 24);
    ACC8(B0, B1, B2);   // u in [base+0, base+8)
    ACC8(B1, B2, B3);   // u in [base+8, base+16)
#undef LOAD8
#undef ACC8

    // ---- weights (needed only from here on) ----
    float wb[5][3];
    {
        const float* p1 = w1 + r * 15;
        const float* p2 = w2 + r * 15;
#pragma unroll
        for (int i = 0; i < 5; ++i)
#pragma unroll
            for (int t = 0; t < 3; ++t) wb[i][t] = p1[i * 3 + t] + p2[i * 3 + t];
    }

    // ---- boundary corrections: wave 0 lanes 0-12 left, wave 3 lanes 0-12
    // right (verified body, R11-R14). out-of-range l: subtract ungated
    // u1,u2,u3; in-range edge l: add (gated - ungated) for x1,x2.
    float d1 = 0.f, d1q = 0.f, d2 = 0.f, d2q = 0.f, d3 = 0.f, d3q = 0.f;
    if ((widx == 0 || widx == 3) && lane < 13) {
        const int l = (widx == 0) ? (lane - 7) : (4090 + lane);
        float u1 = 0.f, u2 = 0.f, u3 = 0.f, g1 = 0.f, g2 = 0.f;
#pragma unroll
        for (int d = 0; d < 15; ++d) {
            const int p = l + d - 7;
            const float xd = ((unsigned)p < (unsigned)LEN) ? row[p] : 0.f;
            const float a1 = C1F(d) * xd;
            const float a2 = C2F(d) * xd;
            u1 += a1; u2 += a2;
            if (d >= 6 && d <= 8) u3 += a1;          // middle group = x3
            const bool gate = ((unsigned)(l - 6 + 3 * (d / 3)) < (unsigned)LEN);
            g1 += gate ? a1 : 0.f;
            g2 += gate ? a2 : 0.f;
        }
        if ((unsigned)l < (unsigned)LEN) {
            d1 = g1 - u1;  d1q = fmaf(g1, g1, -u1 * u1);
            d2 = g2 - u2;  d2q = fmaf(g2, g2, -u2 * u2);
            /* x3: gated == ungated in range -> no delta */
        } else {
            d1 = -u1;  d1q = -u1 * u1;
            d2 = -u2;  d2q = -u2 * u2;
            d3 = -u3;  d3q = -u3 * u3;
        }
    }

    // ---- wave reduce: A[15], SX, deltas[6] ----
#pragma unroll
    for (int off = 32; off > 0; off >>= 1) {
#pragma unroll
        for (int dl = 0; dl < 15; ++dl) A[dl] += __shfl_down(A[dl], off);
        SX += __shfl_down(SX, off);
        d1 += __shfl_down(d1, off);   d1q += __shfl_down(d1q, off);
        d2 += __shfl_down(d2, off);   d2q += __shfl_down(d2q, off);
        d3 += __shfl_down(d3, off);   d3q += __shfl_down(d3q, off);
    }

    // ---- combine quarters via LDS (single barrier, after all mem/FMA) ----
    if (lane == 0) {
#pragma unroll
        for (int dl = 0; dl < 15; ++dl) comb[widx][dl] = A[dl];
        comb[widx][15] = SX;
        comb[widx][16] = d1;  comb[widx][17] = d1q;
        comb[widx][18] = d2;  comb[widx][19] = d2q;
        comb[widx][20] = d3;  comb[widx][21] = d3q;
    }
    __syncthreads();

    if (widx == 0 && lane == 0) {
        float Af[15];
#pragma unroll
        for (int dl = 0; dl < 15; ++dl)
            Af[dl] = (comb[0][dl] + comb[1][dl]) + (comb[2][dl] + comb[3][dl]);
        const float SXf = (comb[0][15] + comb[1][15]) + (comb[2][15] + comb[3][15]);
        const float e1  = comb[0][16] + comb[3][16];
        const float e1q = comb[0][17] + comb[3][17];
        const float e2  = comb[0][18] + comb[3][18];
        const float e2q = comb[0][19] + comb[3][19];
        const float e3  = comb[0][20] + comb[3][20];
        const float e3q = comb[0][21] + comb[3][21];

        // rho-weighted autocorr sums (verified finalize, R11-R14)
        float sq1 = 0.f, sq2 = 0.f;
#pragma unroll
        for (int dl = 0; dl < 15; ++dl) {
            float r1 = 0.f, r2 = 0.f;
#pragma unroll
            for (int d = 0; d + dl < 15; ++d) {
                r1 = fmaf(C1F(d), C1F(d + dl), r1);
                r2 = fmaf(C2F(d), C2F(d + dl), r2);
            }
            const float wA = (dl ? 2.f : 1.f) * Af[dl];
            sq1 = fmaf(r1, wA, sq1);
            sq2 = fmaf(r2, wA, sq2);
        }
        const float c30 = wb[2][0], c31 = wb[2][1], c32 = wb[2][2];
        float sq3 = (c30 * c30 + c31 * c31 + c32 * c32) * Af[0]
                  + 2.f * (c30 * c31 + c31 * c32) * Af[1]
                  + 2.f * (c30 * c32) * Af[2];
        float cs = 0.f;
#pragma unroll
        for (int i = 0; i < 5; ++i)
#pragma unroll
            for (int t = 0; t < 3; ++t) cs += wb[i][t];
        const float c3s = c30 + c31 + c32;

        stats_ws[(0 * REPN + r) * BATCH + b] = fmaf(cs, SXf, e1);
        stats_ws[(1 * REPN + r) * BATCH + b] = sq1 + e1q;
        stats_ws[(2 * REPN + r) * BATCH + b] = fmaf(cs, SXf, e2);  // sum(c2)==sum(c1)
        stats_ws[(3 * REPN + r) * BATCH + b] = sq2 + e2q;
        stats_ws[(4 * REPN + r) * BATCH + b] = fmaf(c3s, SXf, e3);
        stats_ws[(5 * REPN + r) * BATCH + b] = sq3 + e3q;
    }
}

// ===========================================================================
// Pass 2 (R15) — quarter-row per wave (4 rounds each), two-window pipeline
// within each quarter. Rounds are independent (each loads its own 80B
// window); q=0 keeps the k=0 edge round, q=3 the k=15 edge round.
// ===========================================================================
__device__ __forceinline__ void load_fast(const float* __restrict__ row, int e, float* v) {
    const f32x4* q4 = (const f32x4*)(row + e - 8);
#pragma unroll
    for (int t = 0; t < 5; ++t) {
        f32x4 u = q4[t];
        v[4 * t] = u.x; v[4 * t + 1] = u.y; v[4 * t + 2] = u.z; v[4 * t + 3] = u.w;
    }
}

__device__ __forceinline__ void load_slow(const float* __restrict__ row, int e, float* v) {
#pragma unroll
    for (int d = 0; d < 20; ++d) {
        int fi = e - 8 + d;
        v[d] = ((unsigned)fi < (unsigned)LEN) ? row[fi] : 0.f;
    }
}

__global__ __launch_bounds__(256) void pass2_kernel(const float* __restrict__ x,
                                                    const float* __restrict__ w1,
                                                    const float* __restrict__ w2,
                                                    const float* __restrict__ stats_ws,
                                                    const float* __restrict__ g1, const float* __restrict__ b1,
                                                    const float* __restrict__ g2, const float* __restrict__ b2,
                                                    const float* __restrict__ g3, const float* __restrict__ b3,
                                                    float* __restrict__ out) {
    const int wv = (blockIdx.x << 2) | (threadIdx.x >> 6);
    const int lane = threadIdx.x & 63;
    const int rowid = wv >> 2;
    const int q = wv & 3;
    const int r = rowid % REPN;
    const int b = rowid / REPN;
    const int ch = d_tab.rep[r];
    const float* row = x + ((size_t)b * CH + ch) * LEN;

    // BN finalize: lanes load the 32 batch partials (dup across halves), butterfly.
    float p[6];
    const int bb = lane & 31;
#pragma unroll
    for (int qq = 0; qq < 6; ++qq) p[qq] = stats_ws[(qq * REPN + r) * BATCH + bb];
#pragma unroll
    for (int m = 1; m < 32; m <<= 1)
#pragma unroll
        for (int qq = 0; qq < 6; ++qq) p[qq] += __shfl_xor(p[qq], m);

    const double invN = 1.0 / (double)(BATCH * LEN);
    float sc[3], sh[3];
    {
        const float gr[3] = {g1[r], g2[r], g3[r]};
        const float br[3] = {b1[r], b2[r], b3[r]};
#pragma unroll
        for (int qq = 0; qq < 3; ++qq) {
            double mean = (double)p[2 * qq] * invN;
            double var = (double)p[2 * qq + 1] * invN - mean * mean;
            double inv = 1.0 / sqrt(var + 1e-5);
            double scale = (double)gr[qq] * inv;
            sc[qq] = (float)scale;
            sh[qq] = (float)((double)br[qq] - mean * scale);
        }
    }
    const float base = sh[0] + sh[1] + sh[2];

    float wb[5][3];
    const float* p1 = w1 + r * 15;
    const float* p2 = w2 + r * 15;
#pragma unroll
    for (int i = 0; i < 5; ++i)
#pragma unroll
        for (int t = 0; t < 3; ++t) wb[i][t] = p1[i * 3 + t] + p2[i * 3 + t];

    // Combined 15-tap filter (interior): tap d=3k+t applies to v[j+1+d].
    float c[15];
#pragma unroll
    for (int k = 0; k < 5; ++k)
#pragma unroll
        for (int t = 0; t < 3; ++t)
            c[3 * k + t] = fmaf(sc[0], wb[k][t], sc[1] * wb[4 - k][t]);
#pragma unroll
    for (int t = 0; t < 3; ++t) c[6 + t] = fmaf(sc[2], wb[2][t], c[6 + t]);

    float* orow = out + ((size_t)b * CH + r) * LEN;
    float vA[20], vB[20];

#define INTERIOR_QUAD(E, V)                                                       \
    {                                                                             \
        float o[4];                                                               \
        _Pragma("unroll")                                                         \
        for (int j = 0; j < 4; ++j) {                                             \
            float acc = base + V[j + 8];                                          \
            _Pragma("unroll")                                                     \
            for (int d = 0; d < 15; ++d) acc = fmaf(c[d], V[j + 1 + d], acc);     \
            o[j] = acc;                                                           \
        }                                                                         \
        f32x4 t = {o[0], o[1], o[2], o[3]};                                       \
        *(f32x4*)(orow + (E)) = t;                                                \
    }

#define EDGE_QUAD(E, V)                                                           \
    {                                                                             \
        float o[4];                                                               \
        _Pragma("unroll")                                                         \
        for (int j = 0; j < 4; ++j) {                                             \
            const int l = (E) + j;                                                \
            float x1 = 0.f, x2 = 0.f, x3 = 0.f;                                   \
            _Pragma("unroll")                                                     \
            for (int i = 0; i < 5; ++i) {                                         \
                float a1 = fmaf(wb[i][0], V[j + 1 + 3 * i],                       \
                           fmaf(wb[i][1], V[j + 2 + 3 * i],                       \
                                wb[i][2] * V[j + 3 + 3 * i]));                    \
                float a2 = fmaf(wb[i][0], V[j + 13 - 3 * i],                      \
                           fmaf(wb[i][1], V[j + 14 - 3 * i],                      \
                                wb[i][2] * V[j + 15 - 3 * i]));                   \
                if (i == 2) x3 = a1;                                              \
                a1 = ((unsigned)(l - 6 + 3 * i) < (unsigned)LEN) ? a1 : 0.f;      \
                a2 = ((unsigned)(l + 6 - 3 * i) < (unsigned)LEN) ? a2 : 0.f;      \
                x1 += a1; x2 += a2;                                               \
            }                                                                     \
            o[j] = fmaf(sc[0], x1, fmaf(sc[1], x2, fmaf(sc[2], x3, base + V[j + 8]))); \
        }                                                                         \
        f32x4 t = {o[0], o[1], o[2], o[3]};                                       \
        *(f32x4*)(orow + (E)) = t;                                                \
    }

    if (q == 0) {
        { // k = 0 (edge lanes 0,1)
            const int e = 4 * lane;
            if (lane < 2) { load_slow(row, e, vA); EDGE_QUAD(e, vA); }
            else          { load_fast(row, e, vA); INTERIOR_QUAD(e, vA); }
        }
        // k = 1..3, two-window pipeline
        load_fast(row, 4 * lane + 256, vA);
        load_fast(row, 4 * lane + 512, vB);
        INTERIOR_QUAD(4 * lane + 256, vA);
        load_fast(row, 4 * lane + 768, vA);
        INTERIOR_QUAD(4 * lane + 512, vB);
        INTERIOR_QUAD(4 * lane + 768, vA);
    } else if (q == 3) {
        // k = 12..14, two-window pipeline
        load_fast(row, 4 * lane + 256 * 12, vA);
        load_fast(row, 4 * lane + 256 * 13, vB);
        INTERIOR_QUAD(4 * lane + 256 * 12, vA);
        load_fast(row, 4 * lane + 256 * 14, vA);
        INTERIOR_QUAD(4 * lane + 256 * 13, vB);
        INTERIOR_QUAD(4 * lane + 256 * 14, vA);
        { // k = 15 (edge lanes 62,63)
            const int e = 4 * lane + 3840;
            if (lane >= 62) { load_slow(row, e, vA); EDGE_QUAD(e, vA); }
            else            { load_fast(row, e, vA); INTERIOR_QUAD(e, vA); }
        }
    } else {
        // q = 1 or 2: k = 4q..4q+3, all interior, two-window pipeline
        const int kb = q << 2;
        const int e0 = 4 * lane + 256 * kb;
        load_fast(row, e0, vA);
        load_fast(row, e0 + 256, vB);
        INTERIOR_QUAD(e0, vA);
        load_fast(row, e0 + 512, vA);
        INTERIOR_QUAD(e0 + 256, vB);
        load_fast(row, e0 + 768, vB);
        INTERIOR_QUAD(e0 + 512, vA);
        INTERIOR_QUAD(e0 + 768, vB);
    }
#undef INTERIOR_QUAD
#undef EDGE_QUAD
}

extern "C" void kernel_launch(void* const* d_in, const int* in_sizes, int n_in,
                              void* d_out, int out_size, void* d_ws, size_t ws_size,
                              hipStream_t stream) {
    const float* x  = (const float*)d_in[0];
    const float* w1 = (const float*)d_in[1];
    const float* w2 = (const float*)d_in[2];
    const float* g1 = (const float*)d_in[3];
    const float* b1 = (const float*)d_in[4];
    const float* g2 = (const float*)d_in[5];
    const float* b2 = (const float*)d_in[6];
    const float* g3 = (const float*)d_in[7];
    const float* b3 = (const float*)d_in[8];
    float* out = (float*)d_out;
    float* stats_ws = (float*)d_ws;   // 6*198*32 floats = 152 KB

    // pass1: 6336 rep rows (4 quarter-row waves each) + 1856 ghost blocks.
    pass1_kernel<<<NROW + NGHOST, 256, 0, stream>>>(x, w1, w2, stats_ws, out);
    // pass2: 25344 quarter-row waves = 6336 blocks.
    pass2_kernel<<<NROW, 256, 0, stream>>>(x, w1, w2, stats_ws,
                                           g1, b1, g2, b2, g3, b3, out);
}

// Round 16
// 85.665 us; speedup vs baseline: 1.0856x; 1.0856x over previous
//
#include <hip/hip_runtime.h>

#define LEN 4096
#define BATCH 32
#define CH 256
#define REPN 198
#define GHOSTN 58
#define NROW (REPN * BATCH)     /* 6336 */
#define NGHOST (GHOSTN * BATCH) /* 1856 */
#define P1REPBLK 3168           /* 6336 rows x 2 halves / 4 waves */

typedef float f32x4 __attribute__((ext_vector_type(4)));

// ---------------------------------------------------------------------------
// COMPILE-TIME numpy-legacy RNG replication (verified rounds 1-8):
// np.random.seed(123); np.random.choice(256, 58, replace=False)
// ---------------------------------------------------------------------------
struct MTState { unsigned mt[624]; int mti; };
struct Tab { int rep[REPN]; int ghost[GHOSTN]; };

static constexpr unsigned mt_next(MTState& s) {
    if (s.mti >= 624) {
        for (int k = 0; k < 624; ++k) {
            unsigned y = (s.mt[k] & 0x80000000u) | (s.mt[(k + 1) % 624] & 0x7fffffffu);
            s.mt[k] = s.mt[(k + 397) % 624] ^ (y >> 1) ^ ((y & 1u) ? 0x9908b0dfu : 0u);
        }
        s.mti = 0;
    }
    unsigned y = s.mt[s.mti++];
    y ^= y >> 11;
    y ^= (y << 7) & 0x9d2c5680u;
    y ^= (y << 15) & 0xefc60000u;
    y ^= y >> 18;
    return y;
}

static constexpr Tab make_tab() {
    MTState s{};
    s.mt[0] = 123u;
    for (int i = 1; i < 624; ++i)
        s.mt[i] = 1812433253u * (s.mt[i - 1] ^ (s.mt[i - 1] >> 30)) + (unsigned)i;
    s.mti = 624;
    int perm[256] = {};
    for (int i = 0; i < 256; ++i) perm[i] = i;
    for (int i = 255; i > 0; --i) {
        unsigned mask = (unsigned)i;
        mask |= mask >> 1; mask |= mask >> 2; mask |= mask >> 4;
        mask |= mask >> 8; mask |= mask >> 16;
        unsigned j = 0;
        do { j = mt_next(s) & mask; } while (j > (unsigned)i);
        int t = perm[i]; perm[i] = perm[j]; perm[j] = t;
    }
    bool g[256] = {};
    for (int k = 0; k < GHOSTN; ++k) g[perm[k]] = true;
    Tab t{};
    int rc = 0, gc = 0;
    for (int c = 0; c < 256; ++c) {
        if (g[c]) t.ghost[gc++] = c;
        else      t.rep[rc++] = c;
    }
    return t;
}

__constant__ Tab d_tab = make_tab();

// c1[d] = wb[d/3][d%3] (x1 filter, offsets d-7); c2[d] = wb[4-d/3][d%3]
// (x2 = group-reversed filter, same offsets). Verified mapping:
//   x1[l] = sum_d c1[d] x[l+d-7], group i = d/3 gated on 0 <= l-6+3i < LEN
//   x2[l] = sum_d c2[d] x[l+d-7], tap-d gate is the SAME (l-6+3*(d/3))
//   x3[l] = middle 3-tap (d = 6..8 of c1), ungated.
#define C1F(D) wb[(D) / 3][(D) % 3]
#define C2F(D) wb[4 - (D) / 3][(D) % 3]

// ===========================================================================
// Pass 1 — R14 VERBATIM (proven 78.5us): autocorrelation stats at half-row
// per wave; 4 waves = 2 rows x 2 halves; LDS combine, one end barrier.
//   blocks [0, 3168)      : rep stats
//   blocks [3168, 5024)   : ghost copy, one row per block
// ===========================================================================
__global__ __launch_bounds__(256) void pass1_kernel(const float* __restrict__ x,
                                                    const float* __restrict__ w1,
                                                    const float* __restrict__ w2,
                                                    float* __restrict__ stats_ws,
                                                    float* __restrict__ out) {
    const int blk = blockIdx.x;
    if (blk >= P1REPBLK) {
        // ghost pass-through: NT load (never re-read), plain store
        const int g = (blk - P1REPBLK) % GHOSTN;
        const int b = (blk - P1REPBLK) / GHOSTN;
        const int ch = d_tab.ghost[g];
        const f32x4* src = (const f32x4*)(x + ((size_t)b * CH + ch) * LEN);
        f32x4* dst = (f32x4*)(out + ((size_t)b * CH + REPN + g) * LEN);
#pragma unroll
        for (int k = 0; k < 4; ++k) {
            f32x4 t = __builtin_nontemporal_load(&src[threadIdx.x + 256 * k]);
            dst[threadIdx.x + 256 * k] = t;
        }
        return;
    }

    __shared__ float comb[4][22];
    const int widx = threadIdx.x >> 6;
    const int lane = threadIdx.x & 63;
    const int rowid = (blk << 1) | (widx >> 1);
    const int half = widx & 1;
    const int r = rowid % REPN;
    const int b = rowid / REPN;
    const float* row = x + ((size_t)b * CH + d_tab.rep[r]) * LEN;

    // ---- main accumulation: A[0..14], Sx over this lane's 32 elements ----
    float A[15];
#pragma unroll
    for (int dl = 0; dl < 15; ++dl) A[dl] = 0.f;
    float SX = 0.f;
    float B0[8], B1[8], B2[8], B3[8], B4[8], B5[8];
    const int base = (half << 11) + (lane << 5);

#define LOAD8(DST, OFF)                                                           \
    {                                                                             \
        if ((OFF) < LEN) {                                                        \
            const f32x4* q4_ = (const f32x4*)(row + (OFF));                       \
            f32x4 u0_ = q4_[0], u1_ = q4_[1];                                     \
            DST[0] = u0_.x; DST[1] = u0_.y; DST[2] = u0_.z; DST[3] = u0_.w;       \
            DST[4] = u1_.x; DST[5] = u1_.y; DST[6] = u1_.z; DST[7] = u1_.w;       \
        } else {                                                                  \
            _Pragma("unroll")                                                     \
            for (int t = 0; t < 8; ++t) DST[t] = 0.f;                             \
        }                                                                         \
    }

#define ACC8(P, Q, R)                                                             \
    {                                                                             \
        _Pragma("unroll")                                                         \
        for (int j = 0; j < 8; ++j) {                                             \
            const float xj_ = P[j];                                               \
            SX += xj_;                                                            \
            _Pragma("unroll")                                                     \
            for (int dl = 0; dl < 15; ++dl) {                                     \
                const int t_ = j + dl;                                            \
                const float xd_ = (t_ < 8) ? P[t_]                                \
                                 : (t_ < 16) ? Q[t_ - 8] : R[t_ - 16];            \
                A[dl] = fmaf(xj_, xd_, A[dl]);                                    \
            }                                                                     \
        }                                                                         \
    }

    LOAD8(B0, base);
    LOAD8(B1, base + 8);
    LOAD8(B2, base + 16);
    LOAD8(B3, base + 24);
    LOAD8(B4, base + 32);
    LOAD8(B5, base + 40);
    ACC8(B0, B1, B2);   // u in [base+ 0, base+ 8)
    ACC8(B1, B2, B3);   // u in [base+ 8, base+16)
    ACC8(B2, B3, B4);   // u in [base+16, base+24)
    ACC8(B3, B4, B5);   // u in [base+24, base+32)
#undef LOAD8
#undef ACC8

    // ---- weights (needed only from here on) ----
    float wb[5][3];
    {
        const float* p1 = w1 + r * 15;
        const float* p2 = w2 + r * 15;
#pragma unroll
        for (int i = 0; i < 5; ++i)
#pragma unroll
            for (int t = 0; t < 3; ++t) wb[i][t] = p1[i * 3 + t] + p2[i * 3 + t];
    }

    // ---- boundary corrections (half 0 wave only): one output l per lane ----
    float d1 = 0.f, d1q = 0.f, d2 = 0.f, d2q = 0.f, d3 = 0.f, d3q = 0.f;
    if (half == 0 && lane < 26) {
        const int l = (lane <= 12) ? (lane - 7) : (4090 + (lane - 13));
        float u1 = 0.f, u2 = 0.f, u3 = 0.f, g1 = 0.f, g2 = 0.f;
#pragma unroll
        for (int d = 0; d < 15; ++d) {
            const int p = l + d - 7;
            const float xd = ((unsigned)p < (unsigned)LEN) ? row[p] : 0.f;
            const float a1 = C1F(d) * xd;
            const float a2 = C2F(d) * xd;
            u1 += a1; u2 += a2;
            if (d >= 6 && d <= 8) u3 += a1;          // middle group = x3
            const bool gate = ((unsigned)(l - 6 + 3 * (d / 3)) < (unsigned)LEN);
            g1 += gate ? a1 : 0.f;
            g2 += gate ? a2 : 0.f;
        }
        if ((unsigned)l < (unsigned)LEN) {
            d1 = g1 - u1;  d1q = fmaf(g1, g1, -u1 * u1);
            d2 = g2 - u2;  d2q = fmaf(g2, g2, -u2 * u2);
            /* x3: gated == ungated in range -> no delta */
        } else {
            d1 = -u1;  d1q = -u1 * u1;
            d2 = -u2;  d2q = -u2 * u2;
            d3 = -u3;  d3q = -u3 * u3;
        }
    }

    // ---- wave reduce: A[15], SX, deltas[6] ----
#pragma unroll
    for (int off = 32; off > 0; off >>= 1) {
#pragma unroll
        for (int dl = 0; dl < 15; ++dl) A[dl] += __shfl_down(A[dl], off);
        SX += __shfl_down(SX, off);
        d1 += __shfl_down(d1, off);   d1q += __shfl_down(d1q, off);
        d2 += __shfl_down(d2, off);   d2q += __shfl_down(d2q, off);
        d3 += __shfl_down(d3, off);   d3q += __shfl_down(d3q, off);
    }

    // ---- combine halves via LDS (single barrier, after all mem/FMA) ----
    if (lane == 0) {
#pragma unroll
        for (int dl = 0; dl < 15; ++dl) comb[widx][dl] = A[dl];
        comb[widx][15] = SX;
        comb[widx][16] = d1;  comb[widx][17] = d1q;
        comb[widx][18] = d2;  comb[widx][19] = d2q;
        comb[widx][20] = d3;  comb[widx][21] = d3q;
    }
    __syncthreads();

    if (half == 0 && lane == 0) {
        float Af[15];
#pragma unroll
        for (int dl = 0; dl < 15; ++dl) Af[dl] = comb[widx][dl] + comb[widx + 1][dl];
        const float SXf = comb[widx][15] + comb[widx + 1][15];
        const float e1  = comb[widx][16] + comb[widx + 1][16];
        const float e1q = comb[widx][17] + comb[widx + 1][17];
        const float e2  = comb[widx][18] + comb[widx + 1][18];
        const float e2q = comb[widx][19] + comb[widx + 1][19];
        const float e3  = comb[widx][20] + comb[widx + 1][20];
        const float e3q = comb[widx][21] + comb[widx + 1][21];

        // rho-weighted autocorr sums (verified finalize, R11-R14)
        float sq1 = 0.f, sq2 = 0.f;
#pragma unroll
        for (int dl = 0; dl < 15; ++dl) {
            float r1 = 0.f, r2 = 0.f;
#pragma unroll
            for (int d = 0; d + dl < 15; ++d) {
                r1 = fmaf(C1F(d), C1F(d + dl), r1);
                r2 = fmaf(C2F(d), C2F(d + dl), r2);
            }
            const float wA = (dl ? 2.f : 1.f) * Af[dl];
            sq1 = fmaf(r1, wA, sq1);
            sq2 = fmaf(r2, wA, sq2);
        }
        const float c30 = wb[2][0], c31 = wb[2][1], c32 = wb[2][2];
        float sq3 = (c30 * c30 + c31 * c31 + c32 * c32) * Af[0]
                  + 2.f * (c30 * c31 + c31 * c32) * Af[1]
                  + 2.f * (c30 * c32) * Af[2];
        float cs = 0.f;
#pragma unroll
        for (int i = 0; i < 5; ++i)
#pragma unroll
            for (int t = 0; t < 3; ++t) cs += wb[i][t];
        const float c3s = c30 + c31 + c32;

        stats_ws[(0 * REPN + r) * BATCH + b] = fmaf(cs, SXf, e1);
        stats_ws[(1 * REPN + r) * BATCH + b] = sq1 + e1q;
        stats_ws[(2 * REPN + r) * BATCH + b] = fmaf(cs, SXf, e2);  // sum(c2)==sum(c1)
        stats_ws[(3 * REPN + r) * BATCH + b] = sq2 + e2q;
        stats_ws[(4 * REPN + r) * BATCH + b] = fmaf(c3s, SXf, e3);
        stats_ws[(5 * REPN + r) * BATCH + b] = sq3 + e3q;
    }
}

// ===========================================================================
// Pass 2 (R16) — block = ONE ROW (4 waves x 4 rounds, R15's proven round
// bodies) with BN FINALIZE HOISTED: wave 0 computes the ~1000-cycle finalize
// chain ONCE per row (R15's duplication of this chain explains its -14.5us
// regression), publishes sc0/sc1/sc2/base via 4 LDS floats, one barrier.
// Every wave issues its first two window loads BEFORE the barrier so the
// finalize latency hides under them; ~8 blocks/CU overlap the barrier.
// ===========================================================================
__device__ __forceinline__ void load_fast(const float* __restrict__ row, int e, float* v) {
    const f32x4* q4 = (const f32x4*)(row + e - 8);
#pragma unroll
    for (int t = 0; t < 5; ++t) {
        f32x4 u = q4[t];
        v[4 * t] = u.x; v[4 * t + 1] = u.y; v[4 * t + 2] = u.z; v[4 * t + 3] = u.w;
    }
}

__device__ __forceinline__ void load_slow(const float* __restrict__ row, int e, float* v) {
#pragma unroll
    for (int d = 0; d < 20; ++d) {
        int fi = e - 8 + d;
        v[d] = ((unsigned)fi < (unsigned)LEN) ? row[fi] : 0.f;
    }
}

__global__ __launch_bounds__(256) void pass2_kernel(const float* __restrict__ x,
                                                    const float* __restrict__ w1,
                                                    const float* __restrict__ w2,
                                                    const float* __restrict__ stats_ws,
                                                    const float* __restrict__ g1, const float* __restrict__ b1,
                                                    const float* __restrict__ g2, const float* __restrict__ b2,
                                                    const float* __restrict__ g3, const float* __restrict__ b3,
                                                    float* __restrict__ out) {
    __shared__ float cb[4];
    const int lane = threadIdx.x & 63;
    const int q = threadIdx.x >> 6;            // wave = quarter of the row
    const int rowid = blockIdx.x;
    const int r = rowid % REPN;
    const int b = rowid / REPN;
    const int ch = d_tab.rep[r];
    const float* row = x + ((size_t)b * CH + ch) * LEN;
    float* orow = out + ((size_t)b * CH + r) * LEN;

    // ---- issue this wave's first two window loads (hide finalize+barrier) --
    float vA[20], vB[20];
    if (q == 0) {
        const int e = 4 * lane;
        if (lane < 2) load_slow(row, e, vA); else load_fast(row, e, vA);
        load_fast(row, 4 * lane + 256, vB);                 // k=1
    } else if (q == 3) {
        load_fast(row, 4 * lane + 3072, vA);                // k=12
        load_fast(row, 4 * lane + 3328, vB);                // k=13
    } else {
        const int e0 = 4 * lane + 1024 * q;                 // k=4q
        load_fast(row, e0, vA);
        load_fast(row, e0 + 256, vB);
    }

    // ---- wave 0: BN finalize (verbatim R14 chain), publish via LDS ----
    if (q == 0) {
        float p[6];
        const int bb = lane & 31;
#pragma unroll
        for (int qq = 0; qq < 6; ++qq) p[qq] = stats_ws[(qq * REPN + r) * BATCH + bb];
#pragma unroll
        for (int m = 1; m < 32; m <<= 1)
#pragma unroll
            for (int qq = 0; qq < 6; ++qq) p[qq] += __shfl_xor(p[qq], m);

        const double invN = 1.0 / (double)(BATCH * LEN);
        const float gr[3] = {g1[r], g2[r], g3[r]};
        const float br[3] = {b1[r], b2[r], b3[r]};
        float scl[3], shf[3];
#pragma unroll
        for (int qq = 0; qq < 3; ++qq) {
            double mean = (double)p[2 * qq] * invN;
            double var = (double)p[2 * qq + 1] * invN - mean * mean;
            double inv = 1.0 / sqrt(var + 1e-5);
            double scale = (double)gr[qq] * inv;
            scl[qq] = (float)scale;
            shf[qq] = (float)((double)br[qq] - mean * scale);
        }
        if (lane == 0) {
            cb[0] = scl[0]; cb[1] = scl[1]; cb[2] = scl[2];
            cb[3] = shf[0] + shf[1] + shf[2];
        }
    }
    __syncthreads();
    const float sc0 = cb[0], sc1 = cb[1], sc2 = cb[2], base = cb[3];

    // ---- filter build (per thread; cheap) ----
    float wb[5][3];
    {
        const float* p1 = w1 + r * 15;
        const float* p2 = w2 + r * 15;
#pragma unroll
        for (int i = 0; i < 5; ++i)
#pragma unroll
            for (int t = 0; t < 3; ++t) wb[i][t] = p1[i * 3 + t] + p2[i * 3 + t];
    }
    float c[15];
#pragma unroll
    for (int k = 0; k < 5; ++k)
#pragma unroll
        for (int t = 0; t < 3; ++t)
            c[3 * k + t] = fmaf(sc0, wb[k][t], sc1 * wb[4 - k][t]);
#pragma unroll
    for (int t = 0; t < 3; ++t) c[6 + t] = fmaf(sc2, wb[2][t], c[6 + t]);

#define INTERIOR_QUAD(E, V)                                                       \
    {                                                                             \
        float o[4];                                                               \
        _Pragma("unroll")                                                         \
        for (int j = 0; j < 4; ++j) {                                             \
            float acc = base + V[j + 8];                                          \
            _Pragma("unroll")                                                     \
            for (int d = 0; d < 15; ++d) acc = fmaf(c[d], V[j + 1 + d], acc);     \
            o[j] = acc;                                                           \
        }                                                                         \
        f32x4 t = {o[0], o[1], o[2], o[3]};                                       \
        *(f32x4*)(orow + (E)) = t;                                                \
    }

#define EDGE_QUAD(E, V)                                                           \
    {                                                                             \
        float o[4];                                                               \
        _Pragma("unroll")                                                         \
        for (int j = 0; j < 4; ++j) {                                             \
            const int l = (E) + j;                                                \
            float x1 = 0.f, x2 = 0.f, x3 = 0.f;                                   \
            _Pragma("unroll")                                                     \
            for (int i = 0; i < 5; ++i) {                                         \
                float a1 = fmaf(wb[i][0], V[j + 1 + 3 * i],                       \
                           fmaf(wb[i][1], V[j + 2 + 3 * i],                       \
                                wb[i][2] * V[j + 3 + 3 * i]));                    \
                float a2 = fmaf(wb[i][0], V[j + 13 - 3 * i],                      \
                           fmaf(wb[i][1], V[j + 14 - 3 * i],                      \
                                wb[i][2] * V[j + 15 - 3 * i]));                   \
                if (i == 2) x3 = a1;                                              \
                a1 = ((unsigned)(l - 6 + 3 * i) < (unsigned)LEN) ? a1 : 0.f;      \
                a2 = ((unsigned)(l + 6 - 3 * i) < (unsigned)LEN) ? a2 : 0.f;      \
                x1 += a1; x2 += a2;                                               \
            }                                                                     \
            o[j] = fmaf(sc0, x1, fmaf(sc1, x2, fmaf(sc2, x3, base + V[j + 8])));  \
        }                                                                         \
        f32x4 t = {o[0], o[1], o[2], o[3]};                                       \
        *(f32x4*)(orow + (E)) = t;                                                \
    }

    if (q == 0) {
        { // k = 0 (edge lanes 0,1) — window already in vA
            const int e = 4 * lane;
            if (lane < 2) { EDGE_QUAD(e, vA); } else { INTERIOR_QUAD(e, vA); }
        }
        load_fast(row, 4 * lane + 512, vA);                 // prefetch k=2
        INTERIOR_QUAD(4 * lane + 256, vB);                  // k=1
        load_fast(row, 4 * lane + 768, vB);                 // prefetch k=3
        INTERIOR_QUAD(4 * lane + 512, vA);                  // k=2
        INTERIOR_QUAD(4 * lane + 768, vB);                  // k=3
    } else if (q == 3) {
        INTERIOR_QUAD(4 * lane + 3072, vA);                 // k=12
        load_fast(row, 4 * lane + 3584, vA);                // prefetch k=14
        INTERIOR_QUAD(4 * lane + 3328, vB);                 // k=13
        { // prefetch k=15 (edge-aware), compute k=14, then k=15
            const int e = 4 * lane + 3840;
            if (lane >= 62) load_slow(row, e, vB); else load_fast(row, e, vB);
            INTERIOR_QUAD(4 * lane + 3584, vA);             // k=14
            if (lane >= 62) { EDGE_QUAD(e, vB); } else { INTERIOR_QUAD(e, vB); }
        }
    } else {
        // q = 1 or 2: k = 4q..4q+3, all interior
        const int e0 = 4 * lane + 1024 * q;
        INTERIOR_QUAD(e0, vA);
        load_fast(row, e0 + 512, vA);                       // prefetch k+2
        INTERIOR_QUAD(e0 + 256, vB);
        load_fast(row, e0 + 768, vB);                       // prefetch k+3
        INTERIOR_QUAD(e0 + 512, vA);
        INTERIOR_QUAD(e0 + 768, vB);
    }
#undef INTERIOR_QUAD
#undef EDGE_QUAD
}

extern "C" void kernel_launch(void* const* d_in, const int* in_sizes, int n_in,
                              void* d_out, int out_size, void* d_ws, size_t ws_size,
                              hipStream_t stream) {
    const float* x  = (const float*)d_in[0];
    const float* w1 = (const float*)d_in[1];
    const float* w2 = (const float*)d_in[2];
    const float* g1 = (const float*)d_in[3];
    const float* b1 = (const float*)d_in[4];
    const float* g2 = (const float*)d_in[5];
    const float* b2 = (const float*)d_in[6];
    const float* g3 = (const float*)d_in[7];
    const float* b3 = (const float*)d_in[8];
    float* out = (float*)d_out;
    float* stats_ws = (float*)d_ws;   // 6*198*32 floats = 152 KB

    // pass1: 3168 rep-stats blocks (half-row waves, R14) + 1856 ghost blocks.
    pass1_kernel<<<P1REPBLK + NGHOST, 256, 0, stream>>>(x, w1, w2, stats_ws, out);
    // pass2: 6336 row-blocks (4 quarter-waves, finalize once per row).
    pass2_kernel<<<NROW, 256, 0, stream>>>(x, w1, w2, stats_ws,
                                           g1, b1, g2, b2, g3, b3, out);
}

// Round 17
// 82.782 us; speedup vs baseline: 1.1234x; 1.0348x over previous
//
#include <hip/hip_runtime.h>

#define LEN 4096
#define BATCH 32
#define CH 256
#define REPN 198
#define GHOSTN 58
#define NROW (REPN * BATCH)     /* 6336 */
#define NGHOST (GHOSTN * BATCH) /* 1856 */
#define P1REPBLK 3168           /* 6336 rows x 2 halves / 4 waves */
#define P1NTOT (P1REPBLK + NGHOST) /* 5024 */

typedef float f32x4 __attribute__((ext_vector_type(4)));

// ---------------------------------------------------------------------------
// COMPILE-TIME numpy-legacy RNG replication (verified rounds 1-8):
// np.random.seed(123); np.random.choice(256, 58, replace=False)
// ---------------------------------------------------------------------------
struct MTState { unsigned mt[624]; int mti; };
struct Tab { int rep[REPN]; int ghost[GHOSTN]; };

static constexpr unsigned mt_next(MTState& s) {
    if (s.mti >= 624) {
        for (int k = 0; k < 624; ++k) {
            unsigned y = (s.mt[k] & 0x80000000u) | (s.mt[(k + 1) % 624] & 0x7fffffffu);
            s.mt[k] = s.mt[(k + 397) % 624] ^ (y >> 1) ^ ((y & 1u) ? 0x9908b0dfu : 0u);
        }
        s.mti = 0;
    }
    unsigned y = s.mt[s.mti++];
    y ^= y >> 11;
    y ^= (y << 7) & 0x9d2c5680u;
    y ^= (y << 15) & 0xefc60000u;
    y ^= y >> 18;
    return y;
}

static constexpr Tab make_tab() {
    MTState s{};
    s.mt[0] = 123u;
    for (int i = 1; i < 624; ++i)
        s.mt[i] = 1812433253u * (s.mt[i - 1] ^ (s.mt[i - 1] >> 30)) + (unsigned)i;
    s.mti = 624;
    int perm[256] = {};
    for (int i = 0; i < 256; ++i) perm[i] = i;
    for (int i = 255; i > 0; --i) {
        unsigned mask = (unsigned)i;
        mask |= mask >> 1; mask |= mask >> 2; mask |= mask >> 4;
        mask |= mask >> 8; mask |= mask >> 16;
        unsigned j = 0;
        do { j = mt_next(s) & mask; } while (j > (unsigned)i);
        int t = perm[i]; perm[i] = perm[j]; perm[j] = t;
    }
    bool g[256] = {};
    for (int k = 0; k < GHOSTN; ++k) g[perm[k]] = true;
    Tab t{};
    int rc = 0, gc = 0;
    for (int c = 0; c < 256; ++c) {
        if (g[c]) t.ghost[gc++] = c;
        else      t.rep[rc++] = c;
    }
    return t;
}

__constant__ Tab d_tab = make_tab();

// c1[d] = wb[d/3][d%3] (x1 filter, offsets d-7); c2[d] = wb[4-d/3][d%3]
// (x2 = group-reversed filter, same offsets). Verified mapping:
//   x1[l] = sum_d c1[d] x[l+d-7], group i = d/3 gated on 0 <= l-6+3i < LEN
//   x2[l] = sum_d c2[d] x[l+d-7], tap-d gate is the SAME (l-6+3*(d/3))
//   x3[l] = middle 3-tap (d = 6..8 of c1), ungated.
#define C1F(D) wb[(D) / 3][(D) % 3]
#define C2F(D) wb[4 - (D) / 3][(D) % 3]

// ===========================================================================
// Pass 1 (R17) — R14 bodies VERBATIM; ONE change: rep and ghost blocks are
// BRESENHAM-INTERLEAVED across the grid instead of phase-segregated.
// Dispatch is ~in-order, so R14 ran a compute phase (BW idle) then a pure-BW
// ghost tail (VALU idle). Interleaving (every ~2.7th block is ghost) makes
// each CU carry a rep+ghost mix -> ghost HBM traffic hides under rep
// latency stalls; p1 -> max(compute, BW) instead of sum of phases.
//   block i is ghost iff floor((i+1)*NG/NT) > floor(i*NG/NT)  (exact split)
// ===========================================================================
__global__ __launch_bounds__(256) void pass1_kernel(const float* __restrict__ x,
                                                    const float* __restrict__ w1,
                                                    const float* __restrict__ w2,
                                                    float* __restrict__ stats_ws,
                                                    float* __restrict__ out) {
    const int i = blockIdx.x;
    const int gb = (int)(((long long)i * NGHOST) / P1NTOT);
    const bool is_ghost = ((int)(((long long)(i + 1) * NGHOST) / P1NTOT) > gb);
    if (is_ghost) {
        // ghost pass-through: NT load (never re-read), plain store
        const int g = gb % GHOSTN;
        const int b = gb / GHOSTN;
        const int ch = d_tab.ghost[g];
        const f32x4* src = (const f32x4*)(x + ((size_t)b * CH + ch) * LEN);
        f32x4* dst = (f32x4*)(out + ((size_t)b * CH + REPN + g) * LEN);
#pragma unroll
        for (int k = 0; k < 4; ++k) {
            f32x4 t = __builtin_nontemporal_load(&src[threadIdx.x + 256 * k]);
            dst[threadIdx.x + 256 * k] = t;
        }
        return;
    }
    const int blk = i - gb;   // rep block index in [0, P1REPBLK)

    __shared__ float comb[4][22];
    const int widx = threadIdx.x >> 6;
    const int lane = threadIdx.x & 63;
    const int rowid = (blk << 1) | (widx >> 1);
    const int half = widx & 1;
    const int r = rowid % REPN;
    const int b = rowid / REPN;
    const float* row = x + ((size_t)b * CH + d_tab.rep[r]) * LEN;

    // ---- main accumulation: A[0..14], Sx over this lane's 32 elements ----
    float A[15];
#pragma unroll
    for (int dl = 0; dl < 15; ++dl) A[dl] = 0.f;
    float SX = 0.f;
    float B0[8], B1[8], B2[8], B3[8], B4[8], B5[8];
    const int base = (half << 11) + (lane << 5);

#define LOAD8(DST, OFF)                                                           \
    {                                                                             \
        if ((OFF) < LEN) {                                                        \
            const f32x4* q4_ = (const f32x4*)(row + (OFF));                       \
            f32x4 u0_ = q4_[0], u1_ = q4_[1];                                     \
            DST[0] = u0_.x; DST[1] = u0_.y; DST[2] = u0_.z; DST[3] = u0_.w;       \
            DST[4] = u1_.x; DST[5] = u1_.y; DST[6] = u1_.z; DST[7] = u1_.w;       \
        } else {                                                                  \
            _Pragma("unroll")                                                     \
            for (int t = 0; t < 8; ++t) DST[t] = 0.f;                             \
        }                                                                         \
    }

#define ACC8(P, Q, R)                                                             \
    {                                                                             \
        _Pragma("unroll")                                                         \
        for (int j = 0; j < 8; ++j) {                                             \
            const float xj_ = P[j];                                               \
            SX += xj_;                                                            \
            _Pragma("unroll")                                                     \
            for (int dl = 0; dl < 15; ++dl) {                                     \
                const int t_ = j + dl;                                            \
                const float xd_ = (t_ < 8) ? P[t_]                                \
                                 : (t_ < 16) ? Q[t_ - 8] : R[t_ - 16];            \
                A[dl] = fmaf(xj_, xd_, A[dl]);                                    \
            }                                                                     \
        }                                                                         \
    }

    LOAD8(B0, base);
    LOAD8(B1, base + 8);
    LOAD8(B2, base + 16);
    LOAD8(B3, base + 24);
    LOAD8(B4, base + 32);
    LOAD8(B5, base + 40);
    ACC8(B0, B1, B2);   // u in [base+ 0, base+ 8)
    ACC8(B1, B2, B3);   // u in [base+ 8, base+16)
    ACC8(B2, B3, B4);   // u in [base+16, base+24)
    ACC8(B3, B4, B5);   // u in [base+24, base+32)
#undef LOAD8
#undef ACC8

    // ---- weights (needed only from here on) ----
    float wb[5][3];
    {
        const float* p1 = w1 + r * 15;
        const float* p2 = w2 + r * 15;
#pragma unroll
        for (int i2 = 0; i2 < 5; ++i2)
#pragma unroll
            for (int t = 0; t < 3; ++t) wb[i2][t] = p1[i2 * 3 + t] + p2[i2 * 3 + t];
    }

    // ---- boundary corrections (half 0 wave only): one output l per lane ----
    float d1 = 0.f, d1q = 0.f, d2 = 0.f, d2q = 0.f, d3 = 0.f, d3q = 0.f;
    if (half == 0 && lane < 26) {
        const int l = (lane <= 12) ? (lane - 7) : (4090 + (lane - 13));
        float u1 = 0.f, u2 = 0.f, u3 = 0.f, g1 = 0.f, g2 = 0.f;
#pragma unroll
        for (int d = 0; d < 15; ++d) {
            const int p = l + d - 7;
            const float xd = ((unsigned)p < (unsigned)LEN) ? row[p] : 0.f;
            const float a1 = C1F(d) * xd;
            const float a2 = C2F(d) * xd;
            u1 += a1; u2 += a2;
            if (d >= 6 && d <= 8) u3 += a1;          // middle group = x3
            const bool gate = ((unsigned)(l - 6 + 3 * (d / 3)) < (unsigned)LEN);
            g1 += gate ? a1 : 0.f;
            g2 += gate ? a2 : 0.f;
        }
        if ((unsigned)l < (unsigned)LEN) {
            d1 = g1 - u1;  d1q = fmaf(g1, g1, -u1 * u1);
            d2 = g2 - u2;  d2q = fmaf(g2, g2, -u2 * u2);
            /* x3: gated == ungated in range -> no delta */
        } else {
            d1 = -u1;  d1q = -u1 * u1;
            d2 = -u2;  d2q = -u2 * u2;
            d3 = -u3;  d3q = -u3 * u3;
        }
    }

    // ---- wave reduce: A[15], SX, deltas[6] ----
#pragma unroll
    for (int off = 32; off > 0; off >>= 1) {
#pragma unroll
        for (int dl = 0; dl < 15; ++dl) A[dl] += __shfl_down(A[dl], off);
        SX += __shfl_down(SX, off);
        d1 += __shfl_down(d1, off);   d1q += __shfl_down(d1q, off);
        d2 += __shfl_down(d2, off);   d2q += __shfl_down(d2q, off);
        d3 += __shfl_down(d3, off);   d3q += __shfl_down(d3q, off);
    }

    // ---- combine halves via LDS (single barrier, after all mem/FMA) ----
    if (lane == 0) {
#pragma unroll
        for (int dl = 0; dl < 15; ++dl) comb[widx][dl] = A[dl];
        comb[widx][15] = SX;
        comb[widx][16] = d1;  comb[widx][17] = d1q;
        comb[widx][18] = d2;  comb[widx][19] = d2q;
        comb[widx][20] = d3;  comb[widx][21] = d3q;
    }
    __syncthreads();

    if (half == 0 && lane == 0) {
        float Af[15];
#pragma unroll
        for (int dl = 0; dl < 15; ++dl) Af[dl] = comb[widx][dl] + comb[widx + 1][dl];
        const float SXf = comb[widx][15] + comb[widx + 1][15];
        const float e1  = comb[widx][16] + comb[widx + 1][16];
        const float e1q = comb[widx][17] + comb[widx + 1][17];
        const float e2  = comb[widx][18] + comb[widx + 1][18];
        const float e2q = comb[widx][19] + comb[widx + 1][19];
        const float e3  = comb[widx][20] + comb[widx + 1][20];
        const float e3q = comb[widx][21] + comb[widx + 1][21];

        // rho-weighted autocorr sums (verified finalize, R11-R14)
        float sq1 = 0.f, sq2 = 0.f;
#pragma unroll
        for (int dl = 0; dl < 15; ++dl) {
            float r1 = 0.f, r2 = 0.f;
#pragma unroll
            for (int d = 0; d + dl < 15; ++d) {
                r1 = fmaf(C1F(d), C1F(d + dl), r1);
                r2 = fmaf(C2F(d), C2F(d + dl), r2);
            }
            const float wA = (dl ? 2.f : 1.f) * Af[dl];
            sq1 = fmaf(r1, wA, sq1);
            sq2 = fmaf(r2, wA, sq2);
        }
        const float c30 = wb[2][0], c31 = wb[2][1], c32 = wb[2][2];
        float sq3 = (c30 * c30 + c31 * c31 + c32 * c32) * Af[0]
                  + 2.f * (c30 * c31 + c31 * c32) * Af[1]
                  + 2.f * (c30 * c32) * Af[2];
        float cs = 0.f;
#pragma unroll
        for (int i2 = 0; i2 < 5; ++i2)
#pragma unroll
            for (int t = 0; t < 3; ++t) cs += wb[i2][t];
        const float c3s = c30 + c31 + c32;

        stats_ws[(0 * REPN + r) * BATCH + b] = fmaf(cs, SXf, e1);
        stats_ws[(1 * REPN + r) * BATCH + b] = sq1 + e1q;
        stats_ws[(2 * REPN + r) * BATCH + b] = fmaf(cs, SXf, e2);  // sum(c2)==sum(c1)
        stats_ws[(3 * REPN + r) * BATCH + b] = sq2 + e2q;
        stats_ws[(4 * REPN + r) * BATCH + b] = fmaf(c3s, SXf, e3);
        stats_ws[(5 * REPN + r) * BATCH + b] = sq3 + e3q;
    }
}

// ===========================================================================
// Pass 2 — R14 VERBATIM (proven 78.5us): half-row per wave (8 rounds),
// two-window pipeline within each half.
// ===========================================================================
__device__ __forceinline__ void load_fast(const float* __restrict__ row, int e, float* v) {
    const f32x4* q4 = (const f32x4*)(row + e - 8);
#pragma unroll
    for (int t = 0; t < 5; ++t) {
        f32x4 u = q4[t];
        v[4 * t] = u.x; v[4 * t + 1] = u.y; v[4 * t + 2] = u.z; v[4 * t + 3] = u.w;
    }
}

__device__ __forceinline__ void load_slow(const float* __restrict__ row, int e, float* v) {
#pragma unroll
    for (int d = 0; d < 20; ++d) {
        int fi = e - 8 + d;
        v[d] = ((unsigned)fi < (unsigned)LEN) ? row[fi] : 0.f;
    }
}

__global__ __launch_bounds__(256) void pass2_kernel(const float* __restrict__ x,
                                                    const float* __restrict__ w1,
                                                    const float* __restrict__ w2,
                                                    const float* __restrict__ stats_ws,
                                                    const float* __restrict__ g1, const float* __restrict__ b1,
                                                    const float* __restrict__ g2, const float* __restrict__ b2,
                                                    const float* __restrict__ g3, const float* __restrict__ b3,
                                                    float* __restrict__ out) {
    const int wv = (blockIdx.x << 2) | (threadIdx.x >> 6);
    const int lane = threadIdx.x & 63;
    const int rowid = wv >> 1;
    const int half = wv & 1;
    const int r = rowid % REPN;
    const int b = rowid / REPN;
    const int ch = d_tab.rep[r];
    const float* row = x + ((size_t)b * CH + ch) * LEN;

    // BN finalize: lanes load the 32 batch partials (dup across halves), butterfly.
    float p[6];
    const int bb = lane & 31;
#pragma unroll
    for (int q = 0; q < 6; ++q) p[q] = stats_ws[(q * REPN + r) * BATCH + bb];
#pragma unroll
    for (int m = 1; m < 32; m <<= 1)
#pragma unroll
        for (int q = 0; q < 6; ++q) p[q] += __shfl_xor(p[q], m);

    const double invN = 1.0 / (double)(BATCH * LEN);
    float sc[3], sh[3];
    {
        const float gr[3] = {g1[r], g2[r], g3[r]};
        const float br[3] = {b1[r], b2[r], b3[r]};
#pragma unroll
        for (int q = 0; q < 3; ++q) {
            double mean = (double)p[2 * q] * invN;
            double var = (double)p[2 * q + 1] * invN - mean * mean;
            double inv = 1.0 / sqrt(var + 1e-5);
            double scale = (double)gr[q] * inv;
            sc[q] = (float)scale;
            sh[q] = (float)((double)br[q] - mean * scale);
        }
    }
    const float base = sh[0] + sh[1] + sh[2];

    float wb[5][3];
    const float* p1 = w1 + r * 15;
    const float* p2 = w2 + r * 15;
#pragma unroll
    for (int i = 0; i < 5; ++i)
#pragma unroll
        for (int t = 0; t < 3; ++t) wb[i][t] = p1[i * 3 + t] + p2[i * 3 + t];

    // Combined 15-tap filter (interior): tap d=3k+t applies to v[j+1+d].
    float c[15];
#pragma unroll
    for (int k = 0; k < 5; ++k)
#pragma unroll
        for (int t = 0; t < 3; ++t)
            c[3 * k + t] = fmaf(sc[0], wb[k][t], sc[1] * wb[4 - k][t]);
#pragma unroll
    for (int t = 0; t < 3; ++t) c[6 + t] = fmaf(sc[2], wb[2][t], c[6 + t]);

    float* orow = out + ((size_t)b * CH + r) * LEN;
    float vA[20], vB[20];

#define INTERIOR_QUAD(E, V)                                                       \
    {                                                                             \
        float o[4];                                                               \
        _Pragma("unroll")                                                         \
        for (int j = 0; j < 4; ++j) {                                             \
            float acc = base + V[j + 8];                                          \
            _Pragma("unroll")                                                     \
            for (int d = 0; d < 15; ++d) acc = fmaf(c[d], V[j + 1 + d], acc);     \
            o[j] = acc;                                                           \
        }                                                                         \
        f32x4 t = {o[0], o[1], o[2], o[3]};                                       \
        *(f32x4*)(orow + (E)) = t;                                                \
    }

#define EDGE_QUAD(E, V)                                                           \
    {                                                                             \
        float o[4];                                                               \
        _Pragma("unroll")                                                         \
        for (int j = 0; j < 4; ++j) {                                             \
            const int l = (E) + j;                                                \
            float x1 = 0.f, x2 = 0.f, x3 = 0.f;                                   \
            _Pragma("unroll")                                                     \
            for (int i = 0; i < 5; ++i) {                                         \
                float a1 = fmaf(wb[i][0], V[j + 1 + 3 * i],                       \
                           fmaf(wb[i][1], V[j + 2 + 3 * i],                       \
                                wb[i][2] * V[j + 3 + 3 * i]));                    \
                float a2 = fmaf(wb[i][0], V[j + 13 - 3 * i],                      \
                           fmaf(wb[i][1], V[j + 14 - 3 * i],                      \
                                wb[i][2] * V[j + 15 - 3 * i]));                   \
                if (i == 2) x3 = a1;                                              \
                a1 = ((unsigned)(l - 6 + 3 * i) < (unsigned)LEN) ? a1 : 0.f;      \
                a2 = ((unsigned)(l + 6 - 3 * i) < (unsigned)LEN) ? a2 : 0.f;      \
                x1 += a1; x2 += a2;                                               \
            }                                                                     \
            o[j] = fmaf(sc[0], x1, fmaf(sc[1], x2, fmaf(sc[2], x3, base + V[j + 8]))); \
        }                                                                         \
        f32x4 t = {o[0], o[1], o[2], o[3]};                                       \
        *(f32x4*)(orow + (E)) = t;                                                \
    }

    if (half == 0) {
        { // k = 0 (edge lanes 0,1)
            const int e = 4 * lane;
            if (lane < 2) { load_slow(row, e, vA); EDGE_QUAD(e, vA); }
            else          { load_fast(row, e, vA); INTERIOR_QUAD(e, vA); }
        }
        // k = 1..7, two-window pipeline
        load_fast(row, 4 * lane + 256, vA);
#pragma unroll
        for (int kk = 0; kk < 3; ++kk) {
            const int k = 1 + 2 * kk;
            const int eA = 4 * lane + 256 * k;
            const int eB = eA + 256;
            load_fast(row, eB, vB);
            INTERIOR_QUAD(eA, vA);
            load_fast(row, eB + 256, vA);   // k+2 <= 7
            INTERIOR_QUAD(eB, vB);
        }
        INTERIOR_QUAD(4 * lane + 256 * 7, vA);  // k = 7
    } else {
        // k = 8..14, two-window pipeline
        load_fast(row, 4 * lane + 256 * 8, vA);
#pragma unroll
        for (int kk = 0; kk < 3; ++kk) {
            const int k = 8 + 2 * kk;
            const int eA = 4 * lane + 256 * k;
            const int eB = eA + 256;
            load_fast(row, eB, vB);
            INTERIOR_QUAD(eA, vA);
            load_fast(row, eB + 256, vA);   // k+2 <= 14
            INTERIOR_QUAD(eB, vB);
        }
        INTERIOR_QUAD(4 * lane + 256 * 14, vA); // k = 14
        { // k = 15 (edge lanes 62,63)
            const int e = 4 * lane + 3840;
            if (lane >= 62) { load_slow(row, e, vA); EDGE_QUAD(e, vA); }
            else            { load_fast(row, e, vA); INTERIOR_QUAD(e, vA); }
        }
    }
#undef INTERIOR_QUAD
#undef EDGE_QUAD
}

extern "C" void kernel_launch(void* const* d_in, const int* in_sizes, int n_in,
                              void* d_out, int out_size, void* d_ws, size_t ws_size,
                              hipStream_t stream) {
    const float* x  = (const float*)d_in[0];
    const float* w1 = (const float*)d_in[1];
    const float* w2 = (const float*)d_in[2];
    const float* g1 = (const float*)d_in[3];
    const float* b1 = (const float*)d_in[4];
    const float* g2 = (const float*)d_in[5];
    const float* b2 = (const float*)d_in[6];
    const float* g3 = (const float*)d_in[7];
    const float* b3 = (const float*)d_in[8];
    float* out = (float*)d_out;
    float* stats_ws = (float*)d_ws;   // 6*198*32 floats = 152 KB

    // pass1: 5024 blocks, rep/ghost Bresenham-interleaved (R14 bodies).
    pass1_kernel<<<P1NTOT, 256, 0, stream>>>(x, w1, w2, stats_ws, out);
    // pass2: 12672 half-row waves = 3168 blocks (R14 verbatim).
    pass2_kernel<<<P1REPBLK, 256, 0, stream>>>(x, w1, w2, stats_ws,
                                               g1, b1, g2, b2, g3, b3, out);
}

// Round 18
// 80.846 us; speedup vs baseline: 1.1503x; 1.0239x over previous
//
#include <hip/hip_runtime.h>

#define LEN 4096
#define BATCH 32
#define CH 256
#define REPN 198
#define GHOSTN 58
#define NROW (REPN * BATCH)     /* 6336 */
#define NGHOST (GHOSTN * BATCH) /* 1856 */
#define P1REPBLK 3168           /* 6336 rows x 2 halves / 4 waves */
#define STATS_FLOATS (6 * REPN * BATCH)  /* 38016 */
#define CONSTS_PER_CH 19                 /* c[15], sc0..2, base */

typedef float f32x4 __attribute__((ext_vector_type(4)));

// ---------------------------------------------------------------------------
// COMPILE-TIME numpy-legacy RNG replication (verified rounds 1-8):
// np.random.seed(123); np.random.choice(256, 58, replace=False)
// ---------------------------------------------------------------------------
struct MTState { unsigned mt[624]; int mti; };
struct Tab { int rep[REPN]; int ghost[GHOSTN]; };

static constexpr unsigned mt_next(MTState& s) {
    if (s.mti >= 624) {
        for (int k = 0; k < 624; ++k) {
            unsigned y = (s.mt[k] & 0x80000000u) | (s.mt[(k + 1) % 624] & 0x7fffffffu);
            s.mt[k] = s.mt[(k + 397) % 624] ^ (y >> 1) ^ ((y & 1u) ? 0x9908b0dfu : 0u);
        }
        s.mti = 0;
    }
    unsigned y = s.mt[s.mti++];
    y ^= y >> 11;
    y ^= (y << 7) & 0x9d2c5680u;
    y ^= (y << 15) & 0xefc60000u;
    y ^= y >> 18;
    return y;
}

static constexpr Tab make_tab() {
    MTState s{};
    s.mt[0] = 123u;
    for (int i = 1; i < 624; ++i)
        s.mt[i] = 1812433253u * (s.mt[i - 1] ^ (s.mt[i - 1] >> 30)) + (unsigned)i;
    s.mti = 624;
    int perm[256] = {};
    for (int i = 0; i < 256; ++i) perm[i] = i;
    for (int i = 255; i > 0; --i) {
        unsigned mask = (unsigned)i;
        mask |= mask >> 1; mask |= mask >> 2; mask |= mask >> 4;
        mask |= mask >> 8; mask |= mask >> 16;
        unsigned j = 0;
        do { j = mt_next(s) & mask; } while (j > (unsigned)i);
        int t = perm[i]; perm[i] = perm[j]; perm[j] = t;
    }
    bool g[256] = {};
    for (int k = 0; k < GHOSTN; ++k) g[perm[k]] = true;
    Tab t{};
    int rc = 0, gc = 0;
    for (int c = 0; c < 256; ++c) {
        if (g[c]) t.ghost[gc++] = c;
        else      t.rep[rc++] = c;
    }
    return t;
}

__constant__ Tab d_tab = make_tab();

// c1[d] = wb[d/3][d%3] (x1 filter, offsets d-7); c2[d] = wb[4-d/3][d%3]
// (x2 = group-reversed filter, same offsets). Verified mapping:
//   x1[l] = sum_d c1[d] x[l+d-7], group i = d/3 gated on 0 <= l-6+3i < LEN
//   x2[l] = sum_d c2[d] x[l+d-7], tap-d gate is the SAME (l-6+3*(d/3))
//   x3[l] = middle 3-tap (d = 6..8 of c1), ungated.
#define C1F(D) wb[(D) / 3][(D) % 3]
#define C2F(D) wb[4 - (D) / 3][(D) % 3]

// ===========================================================================
// Pass 1 — R14 VERBATIM (proven 78.5us; R17's ghost interleave regressed,
// reverted to segregated): autocorrelation stats at half-row per wave.
//   blocks [0, 3168)      : rep stats
//   blocks [3168, 5024)   : ghost copy, one row per block
// ===========================================================================
__global__ __launch_bounds__(256) void pass1_kernel(const float* __restrict__ x,
                                                    const float* __restrict__ w1,
                                                    const float* __restrict__ w2,
                                                    float* __restrict__ stats_ws,
                                                    float* __restrict__ out) {
    const int blk = blockIdx.x;
    if (blk >= P1REPBLK) {
        // ghost pass-through: NT load (never re-read), plain store
        const int g = (blk - P1REPBLK) % GHOSTN;
        const int b = (blk - P1REPBLK) / GHOSTN;
        const int ch = d_tab.ghost[g];
        const f32x4* src = (const f32x4*)(x + ((size_t)b * CH + ch) * LEN);
        f32x4* dst = (f32x4*)(out + ((size_t)b * CH + REPN + g) * LEN);
#pragma unroll
        for (int k = 0; k < 4; ++k) {
            f32x4 t = __builtin_nontemporal_load(&src[threadIdx.x + 256 * k]);
            dst[threadIdx.x + 256 * k] = t;
        }
        return;
    }

    __shared__ float comb[4][22];
    const int widx = threadIdx.x >> 6;
    const int lane = threadIdx.x & 63;
    const int rowid = (blk << 1) | (widx >> 1);
    const int half = widx & 1;
    const int r = rowid % REPN;
    const int b = rowid / REPN;
    const float* row = x + ((size_t)b * CH + d_tab.rep[r]) * LEN;

    // ---- main accumulation: A[0..14], Sx over this lane's 32 elements ----
    float A[15];
#pragma unroll
    for (int dl = 0; dl < 15; ++dl) A[dl] = 0.f;
    float SX = 0.f;
    float B0[8], B1[8], B2[8], B3[8], B4[8], B5[8];
    const int base = (half << 11) + (lane << 5);

#define LOAD8(DST, OFF)                                                           \
    {                                                                             \
        if ((OFF) < LEN) {                                                        \
            const f32x4* q4_ = (const f32x4*)(row + (OFF));                       \
            f32x4 u0_ = q4_[0], u1_ = q4_[1];                                     \
            DST[0] = u0_.x; DST[1] = u0_.y; DST[2] = u0_.z; DST[3] = u0_.w;       \
            DST[4] = u1_.x; DST[5] = u1_.y; DST[6] = u1_.z; DST[7] = u1_.w;       \
        } else {                                                                  \
            _Pragma("unroll")                                                     \
            for (int t = 0; t < 8; ++t) DST[t] = 0.f;                             \
        }                                                                         \
    }

#define ACC8(P, Q, R)                                                             \
    {                                                                             \
        _Pragma("unroll")                                                         \
        for (int j = 0; j < 8; ++j) {                                             \
            const float xj_ = P[j];                                               \
            SX += xj_;                                                            \
            _Pragma("unroll")                                                     \
            for (int dl = 0; dl < 15; ++dl) {                                     \
                const int t_ = j + dl;                                            \
                const float xd_ = (t_ < 8) ? P[t_]                                \
                                 : (t_ < 16) ? Q[t_ - 8] : R[t_ - 16];            \
                A[dl] = fmaf(xj_, xd_, A[dl]);                                    \
            }                                                                     \
        }                                                                         \
    }

    LOAD8(B0, base);
    LOAD8(B1, base + 8);
    LOAD8(B2, base + 16);
    LOAD8(B3, base + 24);
    LOAD8(B4, base + 32);
    LOAD8(B5, base + 40);
    ACC8(B0, B1, B2);   // u in [base+ 0, base+ 8)
    ACC8(B1, B2, B3);   // u in [base+ 8, base+16)
    ACC8(B2, B3, B4);   // u in [base+16, base+24)
    ACC8(B3, B4, B5);   // u in [base+24, base+32)
#undef LOAD8
#undef ACC8

    // ---- weights (needed only from here on) ----
    float wb[5][3];
    {
        const float* p1 = w1 + r * 15;
        const float* p2 = w2 + r * 15;
#pragma unroll
        for (int i = 0; i < 5; ++i)
#pragma unroll
            for (int t = 0; t < 3; ++t) wb[i][t] = p1[i * 3 + t] + p2[i * 3 + t];
    }

    // ---- boundary corrections (half 0 wave only): one output l per lane ----
    float d1 = 0.f, d1q = 0.f, d2 = 0.f, d2q = 0.f, d3 = 0.f, d3q = 0.f;
    if (half == 0 && lane < 26) {
        const int l = (lane <= 12) ? (lane - 7) : (4090 + (lane - 13));
        float u1 = 0.f, u2 = 0.f, u3 = 0.f, g1 = 0.f, g2 = 0.f;
#pragma unroll
        for (int d = 0; d < 15; ++d) {
            const int p = l + d - 7;
            const float xd = ((unsigned)p < (unsigned)LEN) ? row[p] : 0.f;
            const float a1 = C1F(d) * xd;
            const float a2 = C2F(d) * xd;
            u1 += a1; u2 += a2;
            if (d >= 6 && d <= 8) u3 += a1;          // middle group = x3
            const bool gate = ((unsigned)(l - 6 + 3 * (d / 3)) < (unsigned)LEN);
            g1 += gate ? a1 : 0.f;
            g2 += gate ? a2 : 0.f;
        }
        if ((unsigned)l < (unsigned)LEN) {
            d1 = g1 - u1;  d1q = fmaf(g1, g1, -u1 * u1);
            d2 = g2 - u2;  d2q = fmaf(g2, g2, -u2 * u2);
            /* x3: gated == ungated in range -> no delta */
        } else {
            d1 = -u1;  d1q = -u1 * u1;
            d2 = -u2;  d2q = -u2 * u2;
            d3 = -u3;  d3q = -u3 * u3;
        }
    }

    // ---- wave reduce: A[15], SX, deltas[6] ----
#pragma unroll
    for (int off = 32; off > 0; off >>= 1) {
#pragma unroll
        for (int dl = 0; dl < 15; ++dl) A[dl] += __shfl_down(A[dl], off);
        SX += __shfl_down(SX, off);
        d1 += __shfl_down(d1, off);   d1q += __shfl_down(d1q, off);
        d2 += __shfl_down(d2, off);   d2q += __shfl_down(d2q, off);
        d3 += __shfl_down(d3, off);   d3q += __shfl_down(d3q, off);
    }

    // ---- combine halves via LDS (single barrier, after all mem/FMA) ----
    if (lane == 0) {
#pragma unroll
        for (int dl = 0; dl < 15; ++dl) comb[widx][dl] = A[dl];
        comb[widx][15] = SX;
        comb[widx][16] = d1;  comb[widx][17] = d1q;
        comb[widx][18] = d2;  comb[widx][19] = d2q;
        comb[widx][20] = d3;  comb[widx][21] = d3q;
    }
    __syncthreads();

    if (half == 0 && lane == 0) {
        float Af[15];
#pragma unroll
        for (int dl = 0; dl < 15; ++dl) Af[dl] = comb[widx][dl] + comb[widx + 1][dl];
        const float SXf = comb[widx][15] + comb[widx + 1][15];
        const float e1  = comb[widx][16] + comb[widx + 1][16];
        const float e1q = comb[widx][17] + comb[widx + 1][17];
        const float e2  = comb[widx][18] + comb[widx + 1][18];
        const float e2q = comb[widx][19] + comb[widx + 1][19];
        const float e3  = comb[widx][20] + comb[widx + 1][20];
        const float e3q = comb[widx][21] + comb[widx + 1][21];

        // rho-weighted autocorr sums (verified finalize, R11-R14)
        float sq1 = 0.f, sq2 = 0.f;
#pragma unroll
        for (int dl = 0; dl < 15; ++dl) {
            float r1 = 0.f, r2 = 0.f;
#pragma unroll
            for (int d = 0; d + dl < 15; ++d) {
                r1 = fmaf(C1F(d), C1F(d + dl), r1);
                r2 = fmaf(C2F(d), C2F(d + dl), r2);
            }
            const float wA = (dl ? 2.f : 1.f) * Af[dl];
            sq1 = fmaf(r1, wA, sq1);
            sq2 = fmaf(r2, wA, sq2);
        }
        const float c30 = wb[2][0], c31 = wb[2][1], c32 = wb[2][2];
        float sq3 = (c30 * c30 + c31 * c31 + c32 * c32) * Af[0]
                  + 2.f * (c30 * c31 + c31 * c32) * Af[1]
                  + 2.f * (c30 * c32) * Af[2];
        float cs = 0.f;
#pragma unroll
        for (int i = 0; i < 5; ++i)
#pragma unroll
            for (int t = 0; t < 3; ++t) cs += wb[i][t];
        const float c3s = c30 + c31 + c32;

        stats_ws[(0 * REPN + r) * BATCH + b] = fmaf(cs, SXf, e1);
        stats_ws[(1 * REPN + r) * BATCH + b] = sq1 + e1q;
        stats_ws[(2 * REPN + r) * BATCH + b] = fmaf(cs, SXf, e2);  // sum(c2)==sum(c1)
        stats_ws[(3 * REPN + r) * BATCH + b] = sq2 + e2q;
        stats_ws[(4 * REPN + r) * BATCH + b] = fmaf(c3s, SXf, e3);
        stats_ws[(5 * REPN + r) * BATCH + b] = sq3 + e3q;
    }
}

// ===========================================================================
// Finalize mini-kernel (R18) — per-CHANNEL BN finalize, computed ONCE per
// channel (198 total) instead of once per pass2 wave (12672; R15 quantified
// that duplication at ~6-7us). Verbatim R14 finalize chain; writes 19 floats
// per channel: c[15], sc0, sc1, sc2, base.
// ===========================================================================
__global__ __launch_bounds__(256) void finalize_kernel(
    const float* __restrict__ stats_ws,
    const float* __restrict__ w1, const float* __restrict__ w2,
    const float* __restrict__ g1, const float* __restrict__ b1,
    const float* __restrict__ g2, const float* __restrict__ b2,
    const float* __restrict__ g3, const float* __restrict__ b3,
    float* __restrict__ consts) {
    const int r = (blockIdx.x << 2) | (threadIdx.x >> 6);
    if (r >= REPN) return;
    const int lane = threadIdx.x & 63;

    float p[6];
    const int bb = lane & 31;
#pragma unroll
    for (int q = 0; q < 6; ++q) p[q] = stats_ws[(q * REPN + r) * BATCH + bb];
#pragma unroll
    for (int m = 1; m < 32; m <<= 1)
#pragma unroll
        for (int q = 0; q < 6; ++q) p[q] += __shfl_xor(p[q], m);

    const double invN = 1.0 / (double)(BATCH * LEN);
    float sc[3], sh[3];
    {
        const float gr[3] = {g1[r], g2[r], g3[r]};
        const float br[3] = {b1[r], b2[r], b3[r]};
#pragma unroll
        for (int q = 0; q < 3; ++q) {
            double mean = (double)p[2 * q] * invN;
            double var = (double)p[2 * q + 1] * invN - mean * mean;
            double inv = 1.0 / sqrt(var + 1e-5);
            double scale = (double)gr[q] * inv;
            sc[q] = (float)scale;
            sh[q] = (float)((double)br[q] - mean * scale);
        }
    }

    if (lane == 0) {
        float wb[5][3];
        const float* p1 = w1 + r * 15;
        const float* p2 = w2 + r * 15;
#pragma unroll
        for (int i = 0; i < 5; ++i)
#pragma unroll
            for (int t = 0; t < 3; ++t) wb[i][t] = p1[i * 3 + t] + p2[i * 3 + t];

        float* cc = consts + r * CONSTS_PER_CH;
#pragma unroll
        for (int k = 0; k < 5; ++k)
#pragma unroll
            for (int t = 0; t < 3; ++t)
                cc[3 * k + t] = fmaf(sc[0], wb[k][t], sc[1] * wb[4 - k][t]);
#pragma unroll
        for (int t = 0; t < 3; ++t) cc[6 + t] = fmaf(sc[2], wb[2][t], cc[6 + t]);
        cc[15] = sc[0]; cc[16] = sc[1]; cc[17] = sc[2];
        cc[18] = sh[0] + sh[1] + sh[2];
    }
}

// ===========================================================================
// Pass 2 — R14 structure (half-row per wave, two-window pipeline). PRE=1:
// load the 19 per-channel consts (L2-hot) instead of the ~1000-cycle
// finalize chain; interior lanes never touch w1/w2/g*/b*. PRE=0: R14
// verbatim fallback (used if ws_size lacks the consts region).
// ===========================================================================
__device__ __forceinline__ void load_fast(const float* __restrict__ row, int e, float* v) {
    const f32x4* q4 = (const f32x4*)(row + e - 8);
#pragma unroll
    for (int t = 0; t < 5; ++t) {
        f32x4 u = q4[t];
        v[4 * t] = u.x; v[4 * t + 1] = u.y; v[4 * t + 2] = u.z; v[4 * t + 3] = u.w;
    }
}

__device__ __forceinline__ void load_slow(const float* __restrict__ row, int e, float* v) {
#pragma unroll
    for (int d = 0; d < 20; ++d) {
        int fi = e - 8 + d;
        v[d] = ((unsigned)fi < (unsigned)LEN) ? row[fi] : 0.f;
    }
}

template <int PRE>
__global__ __launch_bounds__(256) void pass2_kernel(const float* __restrict__ x,
                                                    const float* __restrict__ w1,
                                                    const float* __restrict__ w2,
                                                    const float* __restrict__ stats_ws,
                                                    const float* __restrict__ g1, const float* __restrict__ b1,
                                                    const float* __restrict__ g2, const float* __restrict__ b2,
                                                    const float* __restrict__ g3, const float* __restrict__ b3,
                                                    float* __restrict__ out) {
    const int wv = (blockIdx.x << 2) | (threadIdx.x >> 6);
    const int lane = threadIdx.x & 63;
    const int rowid = wv >> 1;
    const int half = wv & 1;
    const int r = rowid % REPN;
    const int b = rowid / REPN;
    const int ch = d_tab.rep[r];
    const float* row = x + ((size_t)b * CH + ch) * LEN;

    float sc0, sc1, sc2, base;
    float c[15];

    if constexpr (PRE) {
        const float* cc = stats_ws + STATS_FLOATS + r * CONSTS_PER_CH;
#pragma unroll
        for (int d = 0; d < 15; ++d) c[d] = cc[d];
        sc0 = cc[15]; sc1 = cc[16]; sc2 = cc[17]; base = cc[18];
    } else {
        // BN finalize (R14 verbatim)
        float p[6];
        const int bb = lane & 31;
#pragma unroll
        for (int q = 0; q < 6; ++q) p[q] = stats_ws[(q * REPN + r) * BATCH + bb];
#pragma unroll
        for (int m = 1; m < 32; m <<= 1)
#pragma unroll
            for (int q = 0; q < 6; ++q) p[q] += __shfl_xor(p[q], m);

        const double invN = 1.0 / (double)(BATCH * LEN);
        float sc[3], sh[3];
        {
            const float gr[3] = {g1[r], g2[r], g3[r]};
            const float br[3] = {b1[r], b2[r], b3[r]};
#pragma unroll
            for (int q = 0; q < 3; ++q) {
                double mean = (double)p[2 * q] * invN;
                double var = (double)p[2 * q + 1] * invN - mean * mean;
                double inv = 1.0 / sqrt(var + 1e-5);
                double scale = (double)gr[q] * inv;
                sc[q] = (float)scale;
                sh[q] = (float)((double)br[q] - mean * scale);
            }
        }
        sc0 = sc[0]; sc1 = sc[1]; sc2 = sc[2];
        base = sh[0] + sh[1] + sh[2];

        float wb[5][3];
        const float* p1 = w1 + r * 15;
        const float* p2 = w2 + r * 15;
#pragma unroll
        for (int i = 0; i < 5; ++i)
#pragma unroll
            for (int t = 0; t < 3; ++t) wb[i][t] = p1[i * 3 + t] + p2[i * 3 + t];
#pragma unroll
        for (int k = 0; k < 5; ++k)
#pragma unroll
            for (int t = 0; t < 3; ++t)
                c[3 * k + t] = fmaf(sc0, wb[k][t], sc1 * wb[4 - k][t]);
#pragma unroll
        for (int t = 0; t < 3; ++t) c[6 + t] = fmaf(sc2, wb[2][t], c[6 + t]);
    }

    float* orow = out + ((size_t)b * CH + r) * LEN;
    float vA[20], vB[20];

#define INTERIOR_QUAD(E, V)                                                       \
    {                                                                             \
        float o[4];                                                               \
        _Pragma("unroll")                                                         \
        for (int j = 0; j < 4; ++j) {                                             \
            float acc = base + V[j + 8];                                          \
            _Pragma("unroll")                                                     \
            for (int d = 0; d < 15; ++d) acc = fmaf(c[d], V[j + 1 + d], acc);     \
            o[j] = acc;                                                           \
        }                                                                         \
        f32x4 t = {o[0], o[1], o[2], o[3]};                                       \
        *(f32x4*)(orow + (E)) = t;                                                \
    }

// EDGE_QUAD expects a local `wb` in scope (built in-branch for PRE).
#define EDGE_QUAD(E, V)                                                           \
    {                                                                             \
        float o[4];                                                               \
        _Pragma("unroll")                                                         \
        for (int j = 0; j < 4; ++j) {                                             \
            const int l = (E) + j;                                                \
            float x1 = 0.f, x2 = 0.f, x3 = 0.f;                                   \
            _Pragma("unroll")                                                     \
            for (int i = 0; i < 5; ++i) {                                         \
                float a1 = fmaf(wb[i][0], V[j + 1 + 3 * i],                       \
                           fmaf(wb[i][1], V[j + 2 + 3 * i],                       \
                                wb[i][2] * V[j + 3 + 3 * i]));                    \
                float a2 = fmaf(wb[i][0], V[j + 13 - 3 * i],                      \
                           fmaf(wb[i][1], V[j + 14 - 3 * i],                      \
                                wb[i][2] * V[j + 15 - 3 * i]));                   \
                if (i == 2) x3 = a1;                                              \
                a1 = ((unsigned)(l - 6 + 3 * i) < (unsigned)LEN) ? a1 : 0.f;      \
                a2 = ((unsigned)(l + 6 - 3 * i) < (unsigned)LEN) ? a2 : 0.f;      \
                x1 += a1; x2 += a2;                                               \
            }                                                                     \
            o[j] = fmaf(sc0, x1, fmaf(sc1, x2, fmaf(sc2, x3, base + V[j + 8])));  \
        }                                                                         \
        f32x4 t = {o[0], o[1], o[2], o[3]};                                       \
        *(f32x4*)(orow + (E)) = t;                                                \
    }

#define BUILD_WB()                                                                \
    float wb[5][3];                                                               \
    {                                                                             \
        const float* p1_ = w1 + r * 15;                                           \
        const float* p2_ = w2 + r * 15;                                           \
        _Pragma("unroll")                                                         \
        for (int i = 0; i < 5; ++i)                                               \
            _Pragma("unroll")                                                     \
            for (int t = 0; t < 3; ++t) wb[i][t] = p1_[i * 3 + t] + p2_[i * 3 + t]; \
    }

    if (half == 0) {
        { // k = 0 (edge lanes 0,1)
            const int e = 4 * lane;
            if (lane < 2) {
                load_slow(row, e, vA);
                BUILD_WB();
                EDGE_QUAD(e, vA);
            } else {
                load_fast(row, e, vA);
                INTERIOR_QUAD(e, vA);
            }
        }
        // k = 1..7, two-window pipeline
        load_fast(row, 4 * lane + 256, vA);
#pragma unroll
        for (int kk = 0; kk < 3; ++kk) {
            const int k = 1 + 2 * kk;
            const int eA = 4 * lane + 256 * k;
            const int eB = eA + 256;
            load_fast(row, eB, vB);
            INTERIOR_QUAD(eA, vA);
            load_fast(row, eB + 256, vA);   // k+2 <= 7
            INTERIOR_QUAD(eB, vB);
        }
        INTERIOR_QUAD(4 * lane + 256 * 7, vA);  // k = 7
    } else {
        // k = 8..14, two-window pipeline
        load_fast(row, 4 * lane + 256 * 8, vA);
#pragma unroll
        for (int kk = 0; kk < 3; ++kk) {
            const int k = 8 + 2 * kk;
            const int eA = 4 * lane + 256 * k;
            const int eB = eA + 256;
            load_fast(row, eB, vB);
            INTERIOR_QUAD(eA, vA);
            load_fast(row, eB + 256, vA);   // k+2 <= 14
            INTERIOR_QUAD(eB, vB);
        }
        INTERIOR_QUAD(4 * lane + 256 * 14, vA); // k = 14
        { // k = 15 (edge lanes 62,63)
            const int e = 4 * lane + 3840;
            if (lane >= 62) {
                load_slow(row, e, vA);
                BUILD_WB();
                EDGE_QUAD(e, vA);
            } else {
                load_fast(row, e, vA);
                INTERIOR_QUAD(e, vA);
            }
        }
    }
#undef INTERIOR_QUAD
#undef EDGE_QUAD
#undef BUILD_WB
}

extern "C" void kernel_launch(void* const* d_in, const int* in_sizes, int n_in,
                              void* d_out, int out_size, void* d_ws, size_t ws_size,
                              hipStream_t stream) {
    const float* x  = (const float*)d_in[0];
    const float* w1 = (const float*)d_in[1];
    const float* w2 = (const float*)d_in[2];
    const float* g1 = (const float*)d_in[3];
    const float* b1 = (const float*)d_in[4];
    const float* g2 = (const float*)d_in[5];
    const float* b2 = (const float*)d_in[6];
    const float* g3 = (const float*)d_in[7];
    const float* b3 = (const float*)d_in[8];
    float* out = (float*)d_out;
    float* stats_ws = (float*)d_ws;

    const size_t need = (size_t)(STATS_FLOATS + REPN * CONSTS_PER_CH) * sizeof(float);

    // pass1: 3168 rep-stats blocks + 1856 ghost blocks (R14 verbatim).
    pass1_kernel<<<P1REPBLK + NGHOST, 256, 0, stream>>>(x, w1, w2, stats_ws, out);

    if (ws_size >= need) {
        // finalize: 198 channel finalizes, once each (50 blocks x 4 waves).
        finalize_kernel<<<(REPN + 3) / 4, 256, 0, stream>>>(
            stats_ws, w1, w2, g1, b1, g2, b2, g3, b3,
            stats_ws + STATS_FLOATS);
        // pass2: 12672 half-row waves; consts preloaded per channel.
        pass2_kernel<1><<<P1REPBLK, 256, 0, stream>>>(x, w1, w2, stats_ws,
                                                      g1, b1, g2, b2, g3, b3, out);
    } else {
        // fallback: R14 verbatim path (finalize per wave).
        pass2_kernel<0><<<P1REPBLK, 256, 0, stream>>>(x, w1, w2, stats_ws,
                                                      g1, b1, g2, b2, g3, b3, out);
    }
}

// Round 19
// 78.792 us; speedup vs baseline: 1.1803x; 1.0261x over previous
//
#include <hip/hip_runtime.h>

#define LEN 4096
#define BATCH 32
#define CH 256
#define REPN 198
#define GHOSTN 58
#define NROW (REPN * BATCH)     /* 6336 */
#define NGHOST (GHOSTN * BATCH) /* 1856 */
#define P1REPBLK 3168           /* 6336 rows x 2 halves / 4 waves */

typedef float f32x4 __attribute__((ext_vector_type(4)));

// ---------------------------------------------------------------------------
// COMPILE-TIME numpy-legacy RNG replication (verified rounds 1-8):
// np.random.seed(123); np.random.choice(256, 58, replace=False)
// ---------------------------------------------------------------------------
struct MTState { unsigned mt[624]; int mti; };
struct Tab { int rep[REPN]; int ghost[GHOSTN]; };

static constexpr unsigned mt_next(MTState& s) {
    if (s.mti >= 624) {
        for (int k = 0; k < 624; ++k) {
            unsigned y = (s.mt[k] & 0x80000000u) | (s.mt[(k + 1) % 624] & 0x7fffffffu);
            s.mt[k] = s.mt[(k + 397) % 624] ^ (y >> 1) ^ ((y & 1u) ? 0x9908b0dfu : 0u);
        }
        s.mti = 0;
    }
    unsigned y = s.mt[s.mti++];
    y ^= y >> 11;
    y ^= (y << 7) & 0x9d2c5680u;
    y ^= (y << 15) & 0xefc60000u;
    y ^= y >> 18;
    return y;
}

static constexpr Tab make_tab() {
    MTState s{};
    s.mt[0] = 123u;
    for (int i = 1; i < 624; ++i)
        s.mt[i] = 1812433253u * (s.mt[i - 1] ^ (s.mt[i - 1] >> 30)) + (unsigned)i;
    s.mti = 624;
    int perm[256] = {};
    for (int i = 0; i < 256; ++i) perm[i] = i;
    for (int i = 255; i > 0; --i) {
        unsigned mask = (unsigned)i;
        mask |= mask >> 1; mask |= mask >> 2; mask |= mask >> 4;
        mask |= mask >> 8; mask |= mask >> 16;
        unsigned j = 0;
        do { j = mt_next(s) & mask; } while (j > (unsigned)i);
        int t = perm[i]; perm[i] = perm[j]; perm[j] = t;
    }
    bool g[256] = {};
    for (int k = 0; k < GHOSTN; ++k) g[perm[k]] = true;
    Tab t{};
    int rc = 0, gc = 0;
    for (int c = 0; c < 256; ++c) {
        if (g[c]) t.ghost[gc++] = c;
        else      t.rep[rc++] = c;
    }
    return t;
}

__constant__ Tab d_tab = make_tab();

// c1[d] = wb[d/3][d%3] (x1 filter, offsets d-7); c2[d] = wb[4-d/3][d%3]
// (x2 = group-reversed filter, same offsets). Verified mapping:
//   x1[l] = sum_d c1[d] x[l+d-7], group i = d/3 gated on 0 <= l-6+3i < LEN
//   x2[l] = sum_d c2[d] x[l+d-7], tap-d gate is the SAME (l-6+3*(d/3))
//   x3[l] = middle 3-tap (d = 6..8 of c1), ungated.
#define C1F(D) wb[(D) / 3][(D) % 3]
#define C2F(D) wb[4 - (D) / 3][(D) % 3]

// ===========================================================================
// Pass 1 — R14 VERBATIM (proven 78.5us): autocorrelation stats at half-row
// per wave; 4 waves = 2 rows x 2 halves; LDS combine, one end barrier.
//   blocks [0, 3168)      : rep stats
//   blocks [3168, 5024)   : ghost copy, one row per block
// ===========================================================================
__global__ __launch_bounds__(256) void pass1_kernel(const float* __restrict__ x,
                                                    const float* __restrict__ w1,
                                                    const float* __restrict__ w2,
                                                    float* __restrict__ stats_ws,
                                                    float* __restrict__ out) {
    const int blk = blockIdx.x;
    if (blk >= P1REPBLK) {
        // ghost pass-through: NT load (never re-read), plain store
        const int g = (blk - P1REPBLK) % GHOSTN;
        const int b = (blk - P1REPBLK) / GHOSTN;
        const int ch = d_tab.ghost[g];
        const f32x4* src = (const f32x4*)(x + ((size_t)b * CH + ch) * LEN);
        f32x4* dst = (f32x4*)(out + ((size_t)b * CH + REPN + g) * LEN);
#pragma unroll
        for (int k = 0; k < 4; ++k) {
            f32x4 t = __builtin_nontemporal_load(&src[threadIdx.x + 256 * k]);
            dst[threadIdx.x + 256 * k] = t;
        }
        return;
    }

    __shared__ float comb[4][22];
    const int widx = threadIdx.x >> 6;
    const int lane = threadIdx.x & 63;
    const int rowid = (blk << 1) | (widx >> 1);
    const int half = widx & 1;
    const int r = rowid % REPN;
    const int b = rowid / REPN;
    const float* row = x + ((size_t)b * CH + d_tab.rep[r]) * LEN;

    // ---- main accumulation: A[0..14], Sx over this lane's 32 elements ----
    float A[15];
#pragma unroll
    for (int dl = 0; dl < 15; ++dl) A[dl] = 0.f;
    float SX = 0.f;
    float B0[8], B1[8], B2[8], B3[8], B4[8], B5[8];
    const int base = (half << 11) + (lane << 5);

#define LOAD8(DST, OFF)                                                           \
    {                                                                             \
        if ((OFF) < LEN) {                                                        \
            const f32x4* q4_ = (const f32x4*)(row + (OFF));                       \
            f32x4 u0_ = q4_[0], u1_ = q4_[1];                                     \
            DST[0] = u0_.x; DST[1] = u0_.y; DST[2] = u0_.z; DST[3] = u0_.w;       \
            DST[4] = u1_.x; DST[5] = u1_.y; DST[6] = u1_.z; DST[7] = u1_.w;       \
        } else {                                                                  \
            _Pragma("unroll")                                                     \
            for (int t = 0; t < 8; ++t) DST[t] = 0.f;                             \
        }                                                                         \
    }

#define ACC8(P, Q, R)                                                             \
    {                                                                             \
        _Pragma("unroll")                                                         \
        for (int j = 0; j < 8; ++j) {                                             \
            const float xj_ = P[j];                                               \
            SX += xj_;                                                            \
            _Pragma("unroll")                                                     \
            for (int dl = 0; dl < 15; ++dl) {                                     \
                const int t_ = j + dl;                                            \
                const float xd_ = (t_ < 8) ? P[t_]                                \
                                 : (t_ < 16) ? Q[t_ - 8] : R[t_ - 16];            \
                A[dl] = fmaf(xj_, xd_, A[dl]);                                    \
            }                                                                     \
        }                                                                         \
    }

    LOAD8(B0, base);
    LOAD8(B1, base + 8);
    LOAD8(B2, base + 16);
    LOAD8(B3, base + 24);
    LOAD8(B4, base + 32);
    LOAD8(B5, base + 40);
    ACC8(B0, B1, B2);   // u in [base+ 0, base+ 8)
    ACC8(B1, B2, B3);   // u in [base+ 8, base+16)
    ACC8(B2, B3, B4);   // u in [base+16, base+24)
    ACC8(B3, B4, B5);   // u in [base+24, base+32)
#undef LOAD8
#undef ACC8

    // ---- weights (needed only from here on) ----
    float wb[5][3];
    {
        const float* p1 = w1 + r * 15;
        const float* p2 = w2 + r * 15;
#pragma unroll
        for (int i = 0; i < 5; ++i)
#pragma unroll
            for (int t = 0; t < 3; ++t) wb[i][t] = p1[i * 3 + t] + p2[i * 3 + t];
    }

    // ---- boundary corrections (half 0 wave only): one output l per lane ----
    float d1 = 0.f, d1q = 0.f, d2 = 0.f, d2q = 0.f, d3 = 0.f, d3q = 0.f;
    if (half == 0 && lane < 26) {
        const int l = (lane <= 12) ? (lane - 7) : (4090 + (lane - 13));
        float u1 = 0.f, u2 = 0.f, u3 = 0.f, g1 = 0.f, g2 = 0.f;
#pragma unroll
        for (int d = 0; d < 15; ++d) {
            const int p = l + d - 7;
            const float xd = ((unsigned)p < (unsigned)LEN) ? row[p] : 0.f;
            const float a1 = C1F(d) * xd;
            const float a2 = C2F(d) * xd;
            u1 += a1; u2 += a2;
            if (d >= 6 && d <= 8) u3 += a1;          // middle group = x3
            const bool gate = ((unsigned)(l - 6 + 3 * (d / 3)) < (unsigned)LEN);
            g1 += gate ? a1 : 0.f;
            g2 += gate ? a2 : 0.f;
        }
        if ((unsigned)l < (unsigned)LEN) {
            d1 = g1 - u1;  d1q = fmaf(g1, g1, -u1 * u1);
            d2 = g2 - u2;  d2q = fmaf(g2, g2, -u2 * u2);
            /* x3: gated == ungated in range -> no delta */
        } else {
            d1 = -u1;  d1q = -u1 * u1;
            d2 = -u2;  d2q = -u2 * u2;
            d3 = -u3;  d3q = -u3 * u3;
        }
    }

    // ---- wave reduce: A[15], SX, deltas[6] ----
#pragma unroll
    for (int off = 32; off > 0; off >>= 1) {
#pragma unroll
        for (int dl = 0; dl < 15; ++dl) A[dl] += __shfl_down(A[dl], off);
        SX += __shfl_down(SX, off);
        d1 += __shfl_down(d1, off);   d1q += __shfl_down(d1q, off);
        d2 += __shfl_down(d2, off);   d2q += __shfl_down(d2q, off);
        d3 += __shfl_down(d3, off);   d3q += __shfl_down(d3q, off);
    }

    // ---- combine halves via LDS (single barrier, after all mem/FMA) ----
    if (lane == 0) {
#pragma unroll
        for (int dl = 0; dl < 15; ++dl) comb[widx][dl] = A[dl];
        comb[widx][15] = SX;
        comb[widx][16] = d1;  comb[widx][17] = d1q;
        comb[widx][18] = d2;  comb[widx][19] = d2q;
        comb[widx][20] = d3;  comb[widx][21] = d3q;
    }
    __syncthreads();

    if (half == 0 && lane == 0) {
        float Af[15];
#pragma unroll
        for (int dl = 0; dl < 15; ++dl) Af[dl] = comb[widx][dl] + comb[widx + 1][dl];
        const float SXf = comb[widx][15] + comb[widx + 1][15];
        const float e1  = comb[widx][16] + comb[widx + 1][16];
        const float e1q = comb[widx][17] + comb[widx + 1][17];
        const float e2  = comb[widx][18] + comb[widx + 1][18];
        const float e2q = comb[widx][19] + comb[widx + 1][19];
        const float e3  = comb[widx][20] + comb[widx + 1][20];
        const float e3q = comb[widx][21] + comb[widx + 1][21];

        // rho-weighted autocorr sums (verified finalize, R11-R14)
        float sq1 = 0.f, sq2 = 0.f;
#pragma unroll
        for (int dl = 0; dl < 15; ++dl) {
            float r1 = 0.f, r2 = 0.f;
#pragma unroll
            for (int d = 0; d + dl < 15; ++d) {
                r1 = fmaf(C1F(d), C1F(d + dl), r1);
                r2 = fmaf(C2F(d), C2F(d + dl), r2);
            }
            const float wA = (dl ? 2.f : 1.f) * Af[dl];
            sq1 = fmaf(r1, wA, sq1);
            sq2 = fmaf(r2, wA, sq2);
        }
        const float c30 = wb[2][0], c31 = wb[2][1], c32 = wb[2][2];
        float sq3 = (c30 * c30 + c31 * c31 + c32 * c32) * Af[0]
                  + 2.f * (c30 * c31 + c31 * c32) * Af[1]
                  + 2.f * (c30 * c32) * Af[2];
        float cs = 0.f;
#pragma unroll
        for (int i = 0; i < 5; ++i)
#pragma unroll
            for (int t = 0; t < 3; ++t) cs += wb[i][t];
        const float c3s = c30 + c31 + c32;

        stats_ws[(0 * REPN + r) * BATCH + b] = fmaf(cs, SXf, e1);
        stats_ws[(1 * REPN + r) * BATCH + b] = sq1 + e1q;
        stats_ws[(2 * REPN + r) * BATCH + b] = fmaf(cs, SXf, e2);  // sum(c2)==sum(c1)
        stats_ws[(3 * REPN + r) * BATCH + b] = sq2 + e2q;
        stats_ws[(4 * REPN + r) * BATCH + b] = fmaf(c3s, SXf, e3);
        stats_ws[(5 * REPN + r) * BATCH + b] = sq3 + e3q;
    }
}

// ===========================================================================
// Pass 2 — R14 VERBATIM (proven 78.5us): half-row per wave (8 rounds),
// per-wave BN finalize, two-window pipeline within each half.
// ===========================================================================
__device__ __forceinline__ void load_fast(const float* __restrict__ row, int e, float* v) {
    const f32x4* q4 = (const f32x4*)(row + e - 8);
#pragma unroll
    for (int t = 0; t < 5; ++t) {
        f32x4 u = q4[t];
        v[4 * t] = u.x; v[4 * t + 1] = u.y; v[4 * t + 2] = u.z; v[4 * t + 3] = u.w;
    }
}

__device__ __forceinline__ void load_slow(const float* __restrict__ row, int e, float* v) {
#pragma unroll
    for (int d = 0; d < 20; ++d) {
        int fi = e - 8 + d;
        v[d] = ((unsigned)fi < (unsigned)LEN) ? row[fi] : 0.f;
    }
}

__global__ __launch_bounds__(256) void pass2_kernel(const float* __restrict__ x,
                                                    const float* __restrict__ w1,
                                                    const float* __restrict__ w2,
                                                    const float* __restrict__ stats_ws,
                                                    const float* __restrict__ g1, const float* __restrict__ b1,
                                                    const float* __restrict__ g2, const float* __restrict__ b2,
                                                    const float* __restrict__ g3, const float* __restrict__ b3,
                                                    float* __restrict__ out) {
    const int wv = (blockIdx.x << 2) | (threadIdx.x >> 6);
    const int lane = threadIdx.x & 63;
    const int rowid = wv >> 1;
    const int half = wv & 1;
    const int r = rowid % REPN;
    const int b = rowid / REPN;
    const int ch = d_tab.rep[r];
    const float* row = x + ((size_t)b * CH + ch) * LEN;

    // BN finalize: lanes load the 32 batch partials (dup across halves), butterfly.
    float p[6];
    const int bb = lane & 31;
#pragma unroll
    for (int q = 0; q < 6; ++q) p[q] = stats_ws[(q * REPN + r) * BATCH + bb];
#pragma unroll
    for (int m = 1; m < 32; m <<= 1)
#pragma unroll
        for (int q = 0; q < 6; ++q) p[q] += __shfl_xor(p[q], m);

    const double invN = 1.0 / (double)(BATCH * LEN);
    float sc[3], sh[3];
    {
        const float gr[3] = {g1[r], g2[r], g3[r]};
        const float br[3] = {b1[r], b2[r], b3[r]};
#pragma unroll
        for (int q = 0; q < 3; ++q) {
            double mean = (double)p[2 * q] * invN;
            double var = (double)p[2 * q + 1] * invN - mean * mean;
            double inv = 1.0 / sqrt(var + 1e-5);
            double scale = (double)gr[q] * inv;
            sc[q] = (float)scale;
            sh[q] = (float)((double)br[q] - mean * scale);
        }
    }
    const float base = sh[0] + sh[1] + sh[2];

    float wb[5][3];
    const float* p1 = w1 + r * 15;
    const float* p2 = w2 + r * 15;
#pragma unroll
    for (int i = 0; i < 5; ++i)
#pragma unroll
        for (int t = 0; t < 3; ++t) wb[i][t] = p1[i * 3 + t] + p2[i * 3 + t];

    // Combined 15-tap filter (interior): tap d=3k+t applies to v[j+1+d].
    float c[15];
#pragma unroll
    for (int k = 0; k < 5; ++k)
#pragma unroll
        for (int t = 0; t < 3; ++t)
            c[3 * k + t] = fmaf(sc[0], wb[k][t], sc[1] * wb[4 - k][t]);
#pragma unroll
    for (int t = 0; t < 3; ++t) c[6 + t] = fmaf(sc[2], wb[2][t], c[6 + t]);

    float* orow = out + ((size_t)b * CH + r) * LEN;
    float vA[20], vB[20];

#define INTERIOR_QUAD(E, V)                                                       \
    {                                                                             \
        float o[4];                                                               \
        _Pragma("unroll")                                                         \
        for (int j = 0; j < 4; ++j) {                                             \
            float acc = base + V[j + 8];                                          \
            _Pragma("unroll")                                                     \
            for (int d = 0; d < 15; ++d) acc = fmaf(c[d], V[j + 1 + d], acc);     \
            o[j] = acc;                                                           \
        }                                                                         \
        f32x4 t = {o[0], o[1], o[2], o[3]};                                       \
        *(f32x4*)(orow + (E)) = t;                                                \
    }

#define EDGE_QUAD(E, V)                                                           \
    {                                                                             \
        float o[4];                                                               \
        _Pragma("unroll")                                                         \
        for (int j = 0; j < 4; ++j) {                                             \
            const int l = (E) + j;                                                \
            float x1 = 0.f, x2 = 0.f, x3 = 0.f;                                   \
            _Pragma("unroll")                                                     \
            for (int i = 0; i < 5; ++i) {                                         \
                float a1 = fmaf(wb[i][0], V[j + 1 + 3 * i],                       \
                           fmaf(wb[i][1], V[j + 2 + 3 * i],                       \
                                wb[i][2] * V[j + 3 + 3 * i]));                    \
                float a2 = fmaf(wb[i][0], V[j + 13 - 3 * i],                      \
                           fmaf(wb[i][1], V[j + 14 - 3 * i],                      \
                                wb[i][2] * V[j + 15 - 3 * i]));                   \
                if (i == 2) x3 = a1;                                              \
                a1 = ((unsigned)(l - 6 + 3 * i) < (unsigned)LEN) ? a1 : 0.f;      \
                a2 = ((unsigned)(l + 6 - 3 * i) < (unsigned)LEN) ? a2 : 0.f;      \
                x1 += a1; x2 += a2;                                               \
            }                                                                     \
            o[j] = fmaf(sc[0], x1, fmaf(sc[1], x2, fmaf(sc[2], x3, base + V[j + 8]))); \
        }                                                                         \
        f32x4 t = {o[0], o[1], o[2], o[3]};                                       \
        *(f32x4*)(orow + (E)) = t;                                                \
    }

    if (half == 0) {
        { // k = 0 (edge lanes 0,1)
            const int e = 4 * lane;
            if (lane < 2) { load_slow(row, e, vA); EDGE_QUAD(e, vA); }
            else          { load_fast(row, e, vA); INTERIOR_QUAD(e, vA); }
        }
        // k = 1..7, two-window pipeline
        load_fast(row, 4 * lane + 256, vA);
#pragma unroll
        for (int kk = 0; kk < 3; ++kk) {
            const int k = 1 + 2 * kk;
            const int eA = 4 * lane + 256 * k;
            const int eB = eA + 256;
            load_fast(row, eB, vB);
            INTERIOR_QUAD(eA, vA);
            load_fast(row, eB + 256, vA);   // k+2 <= 7
            INTERIOR_QUAD(eB, vB);
        }
        INTERIOR_QUAD(4 * lane + 256 * 7, vA);  // k = 7
    } else {
        // k = 8..14, two-window pipeline
        load_fast(row, 4 * lane + 256 * 8, vA);
#pragma unroll
        for (int kk = 0; kk < 3; ++kk) {
            const int k = 8 + 2 * kk;
            const int eA = 4 * lane + 256 * k;
            const int eB = eA + 256;
            load_fast(row, eB, vB);
            INTERIOR_QUAD(eA, vA);
            load_fast(row, eB + 256, vA);   // k+2 <= 14
            INTERIOR_QUAD(eB, vB);
        }
        INTERIOR_QUAD(4 * lane + 256 * 14, vA); // k = 14
        { // k = 15 (edge lanes 62,63)
            const int e = 4 * lane + 3840;
            if (lane >= 62) { load_slow(row, e, vA); EDGE_QUAD(e, vA); }
            else            { load_fast(row, e, vA); INTERIOR_QUAD(e, vA); }
        }
    }
#undef INTERIOR_QUAD
#undef EDGE_QUAD
}

extern "C" void kernel_launch(void* const* d_in, const int* in_sizes, int n_in,
                              void* d_out, int out_size, void* d_ws, size_t ws_size,
                              hipStream_t stream) {
    const float* x  = (const float*)d_in[0];
    const float* w1 = (const float*)d_in[1];
    const float* w2 = (const float*)d_in[2];
    const float* g1 = (const float*)d_in[3];
    const float* b1 = (const float*)d_in[4];
    const float* g2 = (const float*)d_in[5];
    const float* b2 = (const float*)d_in[6];
    const float* g3 = (const float*)d_in[7];
    const float* b3 = (const float*)d_in[8];
    float* out = (float*)d_out;
    float* stats_ws = (float*)d_ws;   // 6*198*32 floats = 152 KB

    // pass1: 3168 rep-stats blocks (half-row waves) + 1856 ghost blocks.
    pass1_kernel<<<P1REPBLK + NGHOST, 256, 0, stream>>>(x, w1, w2, stats_ws, out);
    // pass2: 12672 half-row waves = 3168 blocks.
    pass2_kernel<<<P1REPBLK, 256, 0, stream>>>(x, w1, w2, stats_ws,
                                               g1, b1, g2, b2, g3, b3, out);
}